// Round 1
// baseline (1909.907 us; speedup 1.0000x reference)
//
#include <hip/hip_runtime.h>
#include <math.h>

#define NN    50000
#define DD    64
#define HH    4
#define CREL  264          // 256 fs cols + 4 el + 4 er
#define E_RES 400000
#define E_SEQ 100000
#define E_KNN 400000

// ---------------- CSR build ----------------
__global__ void k_hist(const int* __restrict__ dst, int E, int* __restrict__ cnt){
  int i = blockIdx.x*256 + threadIdx.x;
  if(i<E) atomicAdd(&cnt[dst[i]], 1);
}

__global__ void k_scan(const int* __restrict__ hist, int* __restrict__ rowptr,
                       int* __restrict__ cursor){
  __shared__ int sh[1024];
  const int CH = (NN + 1023)/1024;   // 49
  int t = threadIdx.x;
  for(int r=0;r<3;r++){
    const int* cnt = hist + r*NN;
    int* rp  = rowptr + r*(NN+1);
    int* cur = cursor + r*NN;
    int base = t*CH;
    int loc = 0;
    for(int j=0;j<CH;j++){ int idx=base+j; if(idx<NN) loc += cnt[idx]; }
    int val = loc;
    sh[t]=val; __syncthreads();
    for(int off=1; off<1024; off<<=1){
      int other = (t>=off)? sh[t-off] : 0;
      __syncthreads();
      val += other; sh[t]=val;
      __syncthreads();
    }
    int run = val - loc;             // exclusive prefix of this thread's chunk
    for(int j=0;j<CH;j++){
      int idx=base+j;
      if(idx<NN){ rp[idx]=run; cur[idx]=run; run += cnt[idx]; }
    }
    if(t==1023) rp[NN]=run;          // t=1023's chunk is past NN -> run == total
    __syncthreads();
  }
}

__global__ void k_scatter(const int* __restrict__ src, const int* __restrict__ dst,
                          int E, int* __restrict__ cursor, int* __restrict__ csr){
  int i = blockIdx.x*256 + threadIdx.x;
  if(i<E){ int pos = atomicAdd(&cursor[dst[i]],1); csr[pos]=src[i]; }
}

// ---------------- BN stats ----------------
__global__ void k_bnstats(const float* __restrict__ x, float* __restrict__ stats){
  __shared__ float sh[512];
  int t = threadIdx.x, col = t & 63, rg = t >> 6;
  float s=0.f, q=0.f;
  for(int row = blockIdx.x*4 + rg; row < NN; row += gridDim.x*4){
    float v = x[(size_t)row*64 + col]; s += v; q += v*v;
  }
  sh[t]=s; sh[256+t]=q; __syncthreads();
  if(rg==0){
    s = sh[col]+sh[64+col]+sh[128+col]+sh[192+col];
    q = sh[256+col]+sh[320+col]+sh[384+col]+sh[448+col];
    atomicAdd(&stats[col], s); atomicAdd(&stats[64+col], q);
  }
}

// ---------------- fold BN into weights; build Wal/War columns ----------------
// wbuf layout (floats): [Whm 64*64][bias_hm 64] then per r: [W'_r 64*CREL][bias_r CREL]
__global__ void k_prep(const float* __restrict__ stats, const float* __restrict__ g,
                       const float* __restrict__ be, const float* __restrict__ W,
                       const float* __restrict__ al, const float* __restrict__ ar,
                       const float* __restrict__ b, const float* __restrict__ rW,
                       float* __restrict__ wbuf){
  __shared__ float scale[64], shift[64];
  int t = threadIdx.x;
  if(t<64){
    float mu  = stats[t]*(1.0f/NN);
    float var = stats[64+t]*(1.0f/NN) - mu*mu;
    float sc  = g[t]*rsqrtf(var + 1e-5f);
    scale[t]=sc; shift[t]=be[t]-mu*sc;
  }
  __syncthreads();
  // head-meaned residual matmul: Whm[k][d] = scale[k]*0.25*sum_{r,h} rW[r][k][h*64+d]
  if(t<64){
    int d=t; float bias=0.f;
    for(int k=0;k<64;k++){
      float w=0.f;
      for(int r=0;r<3;r++)
        for(int h=0;h<HH;h++)
          w += rW[((size_t)(r*64+k))*256 + h*64 + d];
      w *= 0.25f;
      bias += shift[k]*w;
      wbuf[k*64+d] = scale[k]*w;
    }
    float bb=0.f;
    for(int r=0;r<3;r++) for(int h=0;h<HH;h++) bb += b[r*256 + h*64 + d];
    wbuf[4096+d] = bias + 0.25f*bb;
  }
  // relation matrices: cols 0..255 = scaled W; 256..259 = Wal; 260..263 = War
  for(int c0=t; c0<3*CREL; c0+=256){
    int r=c0/CREL, c=c0%CREL;
    float* Wo = wbuf + 4160 + r*(64*CREL + CREL);
    float* bo = Wo + 64*CREL;
    float bias=0.f;
    if(c<256){
      for(int k=0;k<64;k++){
        float w = W[((size_t)(r*64+k))*256 + c];
        bias += shift[k]*w;
        Wo[k*CREL+c] = scale[k]*w;
      }
    } else {
      int hh=(c-256)&3;
      const float* av = ((c-256)>=4 ? ar : al) + (r*HH+hh)*64;
      for(int k=0;k<64;k++){
        float w=0.f;
        const float* Wk = W + ((size_t)(r*64+k))*256 + hh*64;
        for(int d2=0;d2<64;d2++) w += Wk[d2]*av[d2];
        bias += shift[k]*w;
        Wo[k*CREL+c] = scale[k]*w;
      }
    }
    bo[c]=bias;
  }
}

// ---------------- matmul: [NN,64] @ [64,CREL] + bias ----------------
__global__ void __launch_bounds__(256)
k_matmulC(const float* __restrict__ A, const float* __restrict__ W,
          const float* __restrict__ bias, float* __restrict__ Y){
  __shared__ float xs[4096];
  int t = threadIdx.x;
  int row0 = blockIdx.x*64;
  for(int f=t; f<1024; f+=256){
    int r=f>>4; int row=row0+r;
    float4 v = (row<NN) ? ((const float4*)A)[(size_t)row*16 + (f&15)]
                        : make_float4(0.f,0.f,0.f,0.f);
    ((float4*)xs)[f]=v;
  }
  __syncthreads();
  int nrows = min(64, NN-row0);
  for(int c=t; c<CREL; c+=256){
    float wreg[64];
    #pragma unroll
    for(int k=0;k<64;k++) wreg[k]=W[k*CREL+c];
    float bs = bias[c];
    for(int r=0;r<nrows;r+=4){
      float a0=bs,a1=bs,a2=bs,a3=bs;
      #pragma unroll
      for(int k=0;k<64;k++){
        float w=wreg[k];
        a0 += xs[(r+0)*64+k]*w;
        a1 += xs[(r+1)*64+k]*w;
        a2 += xs[(r+2)*64+k]*w;
        a3 += xs[(r+3)*64+k]*w;
      }
      size_t base=(size_t)(row0+r)*CREL + c;
      if(row0+r+3 < NN){
        Y[base]=a0; Y[base+CREL]=a1; Y[base+2*CREL]=a2; Y[base+3*CREL]=a3;
      } else {
        if(row0+r   < NN) Y[base]=a0;
        if(row0+r+1 < NN) Y[base+CREL]=a1;
        if(row0+r+2 < NN) Y[base+2*CREL]=a2;
        if(row0+r+3 < NN) Y[base+3*CREL]=a3;
      }
    }
  }
}

// ---------------- matmul: [NN,64] @ [64,64] + bias (opt relu) ----------------
__global__ void __launch_bounds__(256)
k_matmul64(const float* __restrict__ A, const float* __restrict__ W,
           const float* __restrict__ bias, float* __restrict__ Y, int relu){
  __shared__ float xs[4096];
  int t = threadIdx.x;
  int row0 = blockIdx.x*64;
  for(int f=t; f<1024; f+=256){
    int r=f>>4; int row=row0+r;
    float4 v = (row<NN) ? ((const float4*)A)[(size_t)row*16 + (f&15)]
                        : make_float4(0.f,0.f,0.f,0.f);
    ((float4*)xs)[f]=v;
  }
  __syncthreads();
  int c = t & 63, rg = t >> 6;
  float wreg[64];
  #pragma unroll
  for(int k=0;k<64;k++) wreg[k]=W[k*64+c];
  float bs = bias[c];
  for(int r=rg*16; r<rg*16+16; r++){
    int row=row0+r; if(row>=NN) continue;
    float acc=bs;
    #pragma unroll
    for(int k=0;k<64;k++) acc += xs[r*64+k]*wreg[k];
    if(relu) acc=fmaxf(acc,0.f);
    Y[(size_t)row*64+c]=acc;
  }
}

// ---------------- per-node gather aggregation (one wave per dst node) --------
__global__ void __launch_bounds__(256)
k_agg(const float* __restrict__ Y, const int* __restrict__ rowptr,
      const int* __restrict__ csr, float* __restrict__ hacc){
  int wid  = (blockIdx.x*256 + threadIdx.x) >> 6;
  int lane = threadIdx.x & 63;
  if(wid>=NN) return;
  int beg = rowptr[wid], end = rowptr[wid+1];
  float out = 0.f;
  if(end>beg){
    const float* Yv = Y + (size_t)wid*CREL;
    float er0=Yv[260], er1=Yv[261], er2=Yv[262], er3=Yv[263];
    float m0=-1e30f,m1=-1e30f,m2=-1e30f,m3=-1e30f;
    float s0=0.f,s1=0.f,s2=0.f,s3=0.f;
    for(int i=beg;i<end;i++){
      int src = csr[i];
      const float* Ys = Y + (size_t)src*CREL + 256;
      float e0=Ys[0]+er0, e1=Ys[1]+er1, e2=Ys[2]+er2, e3=Ys[3]+er3;
      e0 = e0>0.f? e0 : 0.2f*e0;
      e1 = e1>0.f? e1 : 0.2f*e1;
      e2 = e2>0.f? e2 : 0.2f*e2;
      e3 = e3>0.f? e3 : 0.2f*e3;
      float n0=fmaxf(m0,e0); s0=s0*__expf(m0-n0)+__expf(e0-n0); m0=n0;
      float n1=fmaxf(m1,e1); s1=s1*__expf(m1-n1)+__expf(e1-n1); m1=n1;
      float n2=fmaxf(m2,e2); s2=s2*__expf(m2-n2)+__expf(e2-n2); m2=n2;
      float n3=fmaxf(m3,e3); s3=s3*__expf(m3-n3)+__expf(e3-n3); m3=n3;
    }
    float a0=0.f,a1=0.f,a2=0.f,a3=0.f;
    for(int i=beg;i<end;i++){
      int src = csr[i];
      const float* Ys = Y + (size_t)src*CREL;
      float e0=Ys[256]+er0, e1=Ys[257]+er1, e2=Ys[258]+er2, e3=Ys[259]+er3;
      e0 = e0>0.f? e0 : 0.2f*e0;
      e1 = e1>0.f? e1 : 0.2f*e1;
      e2 = e2>0.f? e2 : 0.2f*e2;
      e3 = e3>0.f? e3 : 0.2f*e3;
      float w0=__expf(e0-m0), w1=__expf(e1-m1), w2=__expf(e2-m2), w3=__expf(e3-m3);
      a0 += w0*Ys[lane];
      a1 += w1*Ys[64+lane];
      a2 += w2*Ys[128+lane];
      a3 += w3*Ys[192+lane];
    }
    out = 0.25f*(a0/s0 + a1/s1 + a2/s2 + a3/s3);
  }
  hacc[(size_t)wid*64 + lane] += out;
}

extern "C" void kernel_launch(void* const* d_in, const int* in_sizes, int n_in,
                              void* d_out, int out_size, void* d_ws, size_t ws_size,
                              hipStream_t stream){
  const float* x      =(const float*)d_in[0];
  const int* src_res  =(const int*)d_in[1];
  const int* dst_res  =(const int*)d_in[2];
  const int* src_seq  =(const int*)d_in[3];
  const int* dst_seq  =(const int*)d_in[4];
  const int* src_knn  =(const int*)d_in[5];
  const int* dst_knn  =(const int*)d_in[6];
  const float* W0 =(const float*)d_in[7];
  const float* al0=(const float*)d_in[8];
  const float* ar0=(const float*)d_in[9];
  const float* b0 =(const float*)d_in[10];
  const float* rW0=(const float*)d_in[11];
  const float* W1 =(const float*)d_in[12];
  const float* al1=(const float*)d_in[13];
  const float* ar1=(const float*)d_in[14];
  const float* b1 =(const float*)d_in[15];
  const float* rW1=(const float*)d_in[16];
  const float* fcW0=(const float*)d_in[17];
  const float* fcb0=(const float*)d_in[18];
  const float* fcW1=(const float*)d_in[19];
  const float* fcb1=(const float*)d_in[20];
  const float* g0 =(const float*)d_in[21];
  const float* be0=(const float*)d_in[22];
  const float* g1 =(const float*)d_in[23];
  const float* be1=(const float*)d_in[24];

  char* ws=(char*)d_ws;
  int*   hist   =(int*)  (ws+0);          // 3*NN ints = 600000 B
  float* stats0 =(float*)(ws+600000);     // 128 f
  float* stats1 =(float*)(ws+600512);     // 128 f
  int*   rowptr =(int*)  (ws+601024);     // 3*(NN+1)
  int*   cursor =(int*)  (ws+1201088);    // 3*NN
  int*   csr    =(int*)  (ws+1801088);    // 900000
  float* wbuf   =(float*)(ws+5401088);    // 55640 f
  float* Y      =(float*)(ws+5623808);    // NN*CREL f = 52.8 MB
  float* hacc   =(float*)(ws+58423808UL); // NN*64 f
  float* xbuf   =(float*)(ws+71223808UL); // NN*64 f

  hipMemsetAsync(ws, 0, 601024, stream);  // hist + both stats buffers

  k_hist<<<(E_RES+255)/256,256,0,stream>>>(dst_res,E_RES,hist);
  k_hist<<<(E_SEQ+255)/256,256,0,stream>>>(dst_seq,E_SEQ,hist+NN);
  k_hist<<<(E_KNN+255)/256,256,0,stream>>>(dst_knn,E_KNN,hist+2*NN);
  k_scan<<<1,1024,0,stream>>>(hist,rowptr,cursor);
  k_scatter<<<(E_RES+255)/256,256,0,stream>>>(src_res,dst_res,E_RES,cursor,csr);
  k_scatter<<<(E_SEQ+255)/256,256,0,stream>>>(src_seq,dst_seq,E_SEQ,cursor+NN,csr+E_RES);
  k_scatter<<<(E_KNN+255)/256,256,0,stream>>>(src_knn,dst_knn,E_KNN,cursor+2*NN,csr+E_RES+E_SEQ);

  const int MBLK=(NN+63)/64;   // 782
  // ---- layer 1 ----
  k_bnstats<<<256,256,0,stream>>>(x,stats0);
  k_prep<<<1,256,0,stream>>>(stats0,g0,be0,W0,al0,ar0,b0,rW0,wbuf);
  k_matmul64<<<MBLK,256,0,stream>>>(x,wbuf,wbuf+4096,hacc,0);   // residual+bias, head-meaned
  for(int r=0;r<3;r++){
    float* Wr=wbuf+4160+r*(64*CREL+CREL);
    int csroff=(r==0)?0:(r==1)?E_RES:(E_RES+E_SEQ);
    k_matmulC<<<MBLK,256,0,stream>>>(x,Wr,Wr+64*CREL,Y);
    k_agg<<<(NN*64)/256,256,0,stream>>>(Y,rowptr+r*(NN+1),csr+csroff,hacc);
  }
  k_matmul64<<<MBLK,256,0,stream>>>(hacc,fcW0,fcb0,xbuf,1);
  // ---- layer 2 ----
  k_bnstats<<<256,256,0,stream>>>(xbuf,stats1);
  k_prep<<<1,256,0,stream>>>(stats1,g1,be1,W1,al1,ar1,b1,rW1,wbuf);
  k_matmul64<<<MBLK,256,0,stream>>>(xbuf,wbuf,wbuf+4096,hacc,0);
  for(int r=0;r<3;r++){
    float* Wr=wbuf+4160+r*(64*CREL+CREL);
    int csroff=(r==0)?0:(r==1)?E_RES:(E_RES+E_SEQ);
    k_matmulC<<<MBLK,256,0,stream>>>(xbuf,Wr,Wr+64*CREL,Y);
    k_agg<<<(NN*64)/256,256,0,stream>>>(Y,rowptr+r*(NN+1),csr+csroff,hacc);
  }
  k_matmul64<<<MBLK,256,0,stream>>>(hacc,fcW1,fcb1,(float*)d_out,1);
}

// Round 2
// 1556.005 us; speedup vs baseline: 1.2274x; 1.2274x over previous
//
#include <hip/hip_runtime.h>
#include <math.h>

#define NN    50000
#define DD    64
#define HH    4
#define CREL  264          // 256 fs cols + 4 el + 4 er
#define E_RES 400000
#define E_SEQ 100000
#define E_KNN 400000
#define SCH   4096
#define SNB   ((NN + SCH - 1)/SCH)   // 13 chunks per relation
#define RPS   (NN + 4)               // rowptr stride (16B-aligned per relation)

// ---------------- CSR build ----------------
__global__ void k_hist(const int* __restrict__ dst, int E, int* __restrict__ cnt){
  int i = blockIdx.x*256 + threadIdx.x;
  if(i<E) atomicAdd(&cnt[dst[i]], 1);
}

// 39 blocks: per-chunk totals, coalesced + shuffle-reduce
__global__ void __launch_bounds__(256)
k_blocksum(const int* __restrict__ hist, int* __restrict__ bsums){
  int r = blockIdx.x / SNB, b = blockIdx.x % SNB;
  const int* cnt = hist + r*NN;
  int t = threadIdx.x;
  int end = min((b+1)*SCH, NN);
  int s = 0;
  for(int j = b*SCH + t; j < end; j += 256) s += cnt[j];
  __shared__ int sh[4];
  for(int off=32; off; off>>=1) s += __shfl_down(s, off, 64);
  int lane = t & 63, w = t >> 6;
  if(lane==0) sh[w]=s;
  __syncthreads();
  if(t==0) bsums[blockIdx.x] = sh[0]+sh[1]+sh[2]+sh[3];
}

// 39 blocks: local scan + chunk offset -> rowptr & cursor
__global__ void __launch_bounds__(256)
k_scanwrite(const int* __restrict__ hist, const int* __restrict__ bsums,
            int* __restrict__ rowptr, int* __restrict__ cursor){
  int r = blockIdx.x / SNB, b = blockIdx.x % SNB;
  const int* cnt = hist + r*NN;
  int* rp  = rowptr + r*RPS;
  int* cur = cursor + r*NN;
  __shared__ int sh_off;
  __shared__ int wtot[4];
  int t = threadIdx.x;
  if(t==0){
    int o=0, tot=0;
    for(int i=0;i<SNB;i++){ int v=bsums[r*SNB+i]; if(i<b) o+=v; tot+=v; }
    sh_off=o;
    if(b==0) rp[NN]=tot;
  }
  int base = b*SCH + t*16;
  int v[16];
  bool full = (base+16 <= NN);
  if(full){
    int4 a0=((const int4*)cnt)[base/4+0];
    int4 a1=((const int4*)cnt)[base/4+1];
    int4 a2=((const int4*)cnt)[base/4+2];
    int4 a3=((const int4*)cnt)[base/4+3];
    v[0]=a0.x;v[1]=a0.y;v[2]=a0.z;v[3]=a0.w;
    v[4]=a1.x;v[5]=a1.y;v[6]=a1.z;v[7]=a1.w;
    v[8]=a2.x;v[9]=a2.y;v[10]=a2.z;v[11]=a2.w;
    v[12]=a3.x;v[13]=a3.y;v[14]=a3.z;v[15]=a3.w;
  } else {
    for(int j=0;j<16;j++){ int idx=base+j; v[j]=(idx<NN)?cnt[idx]:0; }
  }
  int loc=0;
  #pragma unroll
  for(int j=0;j<16;j++) loc += v[j];
  int lane = t & 63, w = t >> 6;
  int inc = loc;
  for(int off=1; off<64; off<<=1){ int n=__shfl_up(inc, off, 64); if(lane>=off) inc+=n; }
  if(lane==63) wtot[w]=inc;
  __syncthreads();
  int woff=0;
  for(int i=0;i<w;i++) woff += wtot[i];
  int run = sh_off + woff + inc - loc;    // exclusive prefix at this thread's first elem
  if(full){
    int o[16];
    #pragma unroll
    for(int j=0;j<16;j++){ o[j]=run; run+=v[j]; }
    ((int4*)rp )[base/4+0]=make_int4(o[0],o[1],o[2],o[3]);
    ((int4*)rp )[base/4+1]=make_int4(o[4],o[5],o[6],o[7]);
    ((int4*)rp )[base/4+2]=make_int4(o[8],o[9],o[10],o[11]);
    ((int4*)rp )[base/4+3]=make_int4(o[12],o[13],o[14],o[15]);
    ((int4*)cur)[base/4+0]=make_int4(o[0],o[1],o[2],o[3]);
    ((int4*)cur)[base/4+1]=make_int4(o[4],o[5],o[6],o[7]);
    ((int4*)cur)[base/4+2]=make_int4(o[8],o[9],o[10],o[11]);
    ((int4*)cur)[base/4+3]=make_int4(o[12],o[13],o[14],o[15]);
  } else {
    for(int j=0;j<16;j++){
      int idx=base+j;
      if(idx<NN){ rp[idx]=run; cur[idx]=run; run+=v[j]; }
    }
  }
}

__global__ void k_scatter(const int* __restrict__ src, const int* __restrict__ dst,
                          int E, int* __restrict__ cursor, int* __restrict__ csr){
  int i = blockIdx.x*256 + threadIdx.x;
  if(i<E){ int pos = atomicAdd(&cursor[dst[i]],1); csr[pos]=src[i]; }
}

// ---------------- BN stats ----------------
__global__ void k_bnstats(const float* __restrict__ x, float* __restrict__ stats){
  __shared__ float sh[512];
  int t = threadIdx.x, col = t & 63, rg = t >> 6;
  float s=0.f, q=0.f;
  for(int row = blockIdx.x*4 + rg; row < NN; row += gridDim.x*4){
    float v = x[(size_t)row*64 + col]; s += v; q += v*v;
  }
  sh[t]=s; sh[256+t]=q; __syncthreads();
  if(rg==0){
    s = sh[col]+sh[64+col]+sh[128+col]+sh[192+col];
    q = sh[256+col]+sh[320+col]+sh[384+col]+sh[448+col];
    atomicAdd(&stats[col], s); atomicAdd(&stats[64+col], q);
  }
}

// ---------------- fold BN into weights; build Wal/War columns ----------------
// wbuf layout (floats): [Whm 64*64][bias_hm 64] then per r: [W'_r 64*CREL][bias_r CREL]
__global__ void k_prep(const float* __restrict__ stats, const float* __restrict__ g,
                       const float* __restrict__ be, const float* __restrict__ W,
                       const float* __restrict__ al, const float* __restrict__ ar,
                       const float* __restrict__ b, const float* __restrict__ rW,
                       float* __restrict__ wbuf){
  __shared__ float scale[64], shift[64];
  int t = threadIdx.x;
  if(t<64){
    float mu  = stats[t]*(1.0f/NN);
    float var = stats[64+t]*(1.0f/NN) - mu*mu;
    float sc  = g[t]*rsqrtf(var + 1e-5f);
    scale[t]=sc; shift[t]=be[t]-mu*sc;
  }
  __syncthreads();
  if(t<64){
    int d=t; float bias=0.f;
    for(int k=0;k<64;k++){
      float w=0.f;
      for(int r=0;r<3;r++)
        for(int h=0;h<HH;h++)
          w += rW[((size_t)(r*64+k))*256 + h*64 + d];
      w *= 0.25f;
      bias += shift[k]*w;
      wbuf[k*64+d] = scale[k]*w;
    }
    float bb=0.f;
    for(int r=0;r<3;r++) for(int h=0;h<HH;h++) bb += b[r*256 + h*64 + d];
    wbuf[4096+d] = bias + 0.25f*bb;
  }
  for(int c0=t; c0<3*CREL; c0+=256){
    int r=c0/CREL, c=c0%CREL;
    float* Wo = wbuf + 4160 + r*(64*CREL + CREL);
    float* bo = Wo + 64*CREL;
    float bias=0.f;
    if(c<256){
      for(int k=0;k<64;k++){
        float w = W[((size_t)(r*64+k))*256 + c];
        bias += shift[k]*w;
        Wo[k*CREL+c] = scale[k]*w;
      }
    } else {
      int hh=(c-256)&3;
      const float* av = ((c-256)>=4 ? ar : al) + (r*HH+hh)*64;
      for(int k=0;k<64;k++){
        float w=0.f;
        const float* Wk = W + ((size_t)(r*64+k))*256 + hh*64;
        for(int d2=0;d2<64;d2++) w += Wk[d2]*av[d2];
        bias += shift[k]*w;
        Wo[k*CREL+c] = scale[k]*w;
      }
    }
    bo[c]=bias;
  }
}

// ---------------- matmul: [NN,64] @ [64,CREL] + bias ----------------
__global__ void __launch_bounds__(256)
k_matmulC(const float* __restrict__ A, const float* __restrict__ W,
          const float* __restrict__ bias, float* __restrict__ Y){
  __shared__ float xs[4096];
  int t = threadIdx.x;
  int row0 = blockIdx.x*64;
  for(int f=t; f<1024; f+=256){
    int r=f>>4; int row=row0+r;
    float4 v = (row<NN) ? ((const float4*)A)[(size_t)row*16 + (f&15)]
                        : make_float4(0.f,0.f,0.f,0.f);
    ((float4*)xs)[f]=v;
  }
  __syncthreads();
  int nrows = min(64, NN-row0);
  for(int c=t; c<CREL; c+=256){
    float wreg[64];
    #pragma unroll
    for(int k=0;k<64;k++) wreg[k]=W[k*CREL+c];
    float bs = bias[c];
    for(int r=0;r<nrows;r+=4){
      float a0=bs,a1=bs,a2=bs,a3=bs;
      #pragma unroll
      for(int k=0;k<64;k++){
        float w=wreg[k];
        a0 += xs[(r+0)*64+k]*w;
        a1 += xs[(r+1)*64+k]*w;
        a2 += xs[(r+2)*64+k]*w;
        a3 += xs[(r+3)*64+k]*w;
      }
      size_t base=(size_t)(row0+r)*CREL + c;
      if(row0+r+3 < NN){
        Y[base]=a0; Y[base+CREL]=a1; Y[base+2*CREL]=a2; Y[base+3*CREL]=a3;
      } else {
        if(row0+r   < NN) Y[base]=a0;
        if(row0+r+1 < NN) Y[base+CREL]=a1;
        if(row0+r+2 < NN) Y[base+2*CREL]=a2;
        if(row0+r+3 < NN) Y[base+3*CREL]=a3;
      }
    }
  }
}

// ---------------- matmul: [NN,64] @ [64,64] + bias (opt relu) ----------------
__global__ void __launch_bounds__(256)
k_matmul64(const float* __restrict__ A, const float* __restrict__ W,
           const float* __restrict__ bias, float* __restrict__ Y, int relu){
  __shared__ float xs[4096];
  int t = threadIdx.x;
  int row0 = blockIdx.x*64;
  for(int f=t; f<1024; f+=256){
    int r=f>>4; int row=row0+r;
    float4 v = (row<NN) ? ((const float4*)A)[(size_t)row*16 + (f&15)]
                        : make_float4(0.f,0.f,0.f,0.f);
    ((float4*)xs)[f]=v;
  }
  __syncthreads();
  int c = t & 63, rg = t >> 6;
  float wreg[64];
  #pragma unroll
  for(int k=0;k<64;k++) wreg[k]=W[k*64+c];
  float bs = bias[c];
  for(int r=rg*16; r<rg*16+16; r++){
    int row=row0+r; if(row>=NN) continue;
    float acc=bs;
    #pragma unroll
    for(int k=0;k<64;k++) acc += xs[r*64+k]*wreg[k];
    if(relu) acc=fmaxf(acc,0.f);
    Y[(size_t)row*64+c]=acc;
  }
}

// ---------------- per-node gather aggregation (one wave per dst node) --------
__global__ void __launch_bounds__(256)
k_agg(const float* __restrict__ Y, const int* __restrict__ rowptr,
      const int* __restrict__ csr, float* __restrict__ hacc){
  int wid  = (blockIdx.x*256 + threadIdx.x) >> 6;
  int lane = threadIdx.x & 63;
  if(wid>=NN) return;
  int beg = rowptr[wid], end = rowptr[wid+1];
  float out = 0.f;
  if(end>beg){
    const float* Yv = Y + (size_t)wid*CREL;
    float er0=Yv[260], er1=Yv[261], er2=Yv[262], er3=Yv[263];
    float m0=-1e30f,m1=-1e30f,m2=-1e30f,m3=-1e30f;
    float s0=0.f,s1=0.f,s2=0.f,s3=0.f;
    for(int i=beg;i<end;i++){
      int src = csr[i];
      const float* Ys = Y + (size_t)src*CREL + 256;
      float e0=Ys[0]+er0, e1=Ys[1]+er1, e2=Ys[2]+er2, e3=Ys[3]+er3;
      e0 = e0>0.f? e0 : 0.2f*e0;
      e1 = e1>0.f? e1 : 0.2f*e1;
      e2 = e2>0.f? e2 : 0.2f*e2;
      e3 = e3>0.f? e3 : 0.2f*e3;
      float n0=fmaxf(m0,e0); s0=s0*__expf(m0-n0)+__expf(e0-n0); m0=n0;
      float n1=fmaxf(m1,e1); s1=s1*__expf(m1-n1)+__expf(e1-n1); m1=n1;
      float n2=fmaxf(m2,e2); s2=s2*__expf(m2-n2)+__expf(e2-n2); m2=n2;
      float n3=fmaxf(m3,e3); s3=s3*__expf(m3-n3)+__expf(e3-n3); m3=n3;
    }
    float a0=0.f,a1=0.f,a2=0.f,a3=0.f;
    for(int i=beg;i<end;i++){
      int src = csr[i];
      const float* Ys = Y + (size_t)src*CREL;
      float e0=Ys[256]+er0, e1=Ys[257]+er1, e2=Ys[258]+er2, e3=Ys[259]+er3;
      e0 = e0>0.f? e0 : 0.2f*e0;
      e1 = e1>0.f? e1 : 0.2f*e1;
      e2 = e2>0.f? e2 : 0.2f*e2;
      e3 = e3>0.f? e3 : 0.2f*e3;
      float w0=__expf(e0-m0), w1=__expf(e1-m1), w2=__expf(e2-m2), w3=__expf(e3-m3);
      a0 += w0*Ys[lane];
      a1 += w1*Ys[64+lane];
      a2 += w2*Ys[128+lane];
      a3 += w3*Ys[192+lane];
    }
    out = 0.25f*(a0/s0 + a1/s1 + a2/s2 + a3/s3);
  }
  hacc[(size_t)wid*64 + lane] += out;
}

extern "C" void kernel_launch(void* const* d_in, const int* in_sizes, int n_in,
                              void* d_out, int out_size, void* d_ws, size_t ws_size,
                              hipStream_t stream){
  const float* x      =(const float*)d_in[0];
  const int* src_res  =(const int*)d_in[1];
  const int* dst_res  =(const int*)d_in[2];
  const int* src_seq  =(const int*)d_in[3];
  const int* dst_seq  =(const int*)d_in[4];
  const int* src_knn  =(const int*)d_in[5];
  const int* dst_knn  =(const int*)d_in[6];
  const float* W0 =(const float*)d_in[7];
  const float* al0=(const float*)d_in[8];
  const float* ar0=(const float*)d_in[9];
  const float* b0 =(const float*)d_in[10];
  const float* rW0=(const float*)d_in[11];
  const float* W1 =(const float*)d_in[12];
  const float* al1=(const float*)d_in[13];
  const float* ar1=(const float*)d_in[14];
  const float* b1 =(const float*)d_in[15];
  const float* rW1=(const float*)d_in[16];
  const float* fcW0=(const float*)d_in[17];
  const float* fcb0=(const float*)d_in[18];
  const float* fcW1=(const float*)d_in[19];
  const float* fcb1=(const float*)d_in[20];
  const float* g0 =(const float*)d_in[21];
  const float* be0=(const float*)d_in[22];
  const float* g1 =(const float*)d_in[23];
  const float* be1=(const float*)d_in[24];

  char* ws=(char*)d_ws;
  int*   hist   =(int*)  (ws+0);          // 3*NN ints = 600000 B
  float* stats0 =(float*)(ws+600000);     // 128 f
  float* stats1 =(float*)(ws+600512);     // 128 f
  int*   rowptr =(int*)  (ws+601024);     // 3*RPS ints
  int*   cursor =(int*)  (ws+1201088);    // 3*NN
  int*   csr    =(int*)  (ws+1801088);    // 900000
  float* wbuf   =(float*)(ws+5401088);    // 55640 f -> ends 5623648
  int*   bsums  =(int*)  (ws+5623648);    // 39 ints (gap before Y)
  float* Y      =(float*)(ws+5623808);    // NN*CREL f = 52.8 MB
  float* hacc   =(float*)(ws+58423808UL); // NN*64 f
  float* xbuf   =(float*)(ws+71223808UL); // NN*64 f

  hipMemsetAsync(ws, 0, 601024, stream);  // hist + both stats buffers

  k_hist<<<(E_RES+255)/256,256,0,stream>>>(dst_res,E_RES,hist);
  k_hist<<<(E_SEQ+255)/256,256,0,stream>>>(dst_seq,E_SEQ,hist+NN);
  k_hist<<<(E_KNN+255)/256,256,0,stream>>>(dst_knn,E_KNN,hist+2*NN);
  k_blocksum<<<3*SNB,256,0,stream>>>(hist,bsums);
  k_scanwrite<<<3*SNB,256,0,stream>>>(hist,bsums,rowptr,cursor);
  k_scatter<<<(E_RES+255)/256,256,0,stream>>>(src_res,dst_res,E_RES,cursor,csr);
  k_scatter<<<(E_SEQ+255)/256,256,0,stream>>>(src_seq,dst_seq,E_SEQ,cursor+NN,csr+E_RES);
  k_scatter<<<(E_KNN+255)/256,256,0,stream>>>(src_knn,dst_knn,E_KNN,cursor+2*NN,csr+E_RES+E_SEQ);

  const int MBLK=(NN+63)/64;   // 782
  // ---- layer 1 ----
  k_bnstats<<<256,256,0,stream>>>(x,stats0);
  k_prep<<<1,256,0,stream>>>(stats0,g0,be0,W0,al0,ar0,b0,rW0,wbuf);
  k_matmul64<<<MBLK,256,0,stream>>>(x,wbuf,wbuf+4096,hacc,0);   // residual+bias, head-meaned
  for(int r=0;r<3;r++){
    float* Wr=wbuf+4160+r*(64*CREL+CREL);
    int csroff=(r==0)?0:(r==1)?E_RES:(E_RES+E_SEQ);
    k_matmulC<<<MBLK,256,0,stream>>>(x,Wr,Wr+64*CREL,Y);
    k_agg<<<(NN*64)/256,256,0,stream>>>(Y,rowptr+r*RPS,csr+csroff,hacc);
  }
  k_matmul64<<<MBLK,256,0,stream>>>(hacc,fcW0,fcb0,xbuf,1);
  // ---- layer 2 ----
  k_bnstats<<<256,256,0,stream>>>(xbuf,stats1);
  k_prep<<<1,256,0,stream>>>(stats1,g1,be1,W1,al1,ar1,b1,rW1,wbuf);
  k_matmul64<<<MBLK,256,0,stream>>>(xbuf,wbuf,wbuf+4096,hacc,0);
  for(int r=0;r<3;r++){
    float* Wr=wbuf+4160+r*(64*CREL+CREL);
    int csroff=(r==0)?0:(r==1)?E_RES:(E_RES+E_SEQ);
    k_matmulC<<<MBLK,256,0,stream>>>(xbuf,Wr,Wr+64*CREL,Y);
    k_agg<<<(NN*64)/256,256,0,stream>>>(Y,rowptr+r*RPS,csr+csroff,hacc);
  }
  k_matmul64<<<MBLK,256,0,stream>>>(hacc,fcW1,fcb1,(float*)d_out,1);
}

// Round 3
// 1243.907 us; speedup vs baseline: 1.5354x; 1.2509x over previous
//
#include <hip/hip_runtime.h>
#include <math.h>

#define NN    50000
#define DD    64
#define HH    4
#define CREL  264          // 256 fs cols + 4 el + 4 er
#define E_RES 400000
#define E_SEQ 100000
#define E_KNN 400000
#define SCH   4096
#define SNB   ((NN + SCH - 1)/SCH)   // 13 chunks per relation
#define RPS   (NN + 4)               // rowptr stride (16B-aligned per relation)

// ---------------- CSR build ----------------
__global__ void k_hist(const int* __restrict__ dst, int E, int* __restrict__ cnt){
  int i = blockIdx.x*256 + threadIdx.x;
  if(i<E) atomicAdd(&cnt[dst[i]], 1);
}

__global__ void __launch_bounds__(256)
k_blocksum(const int* __restrict__ hist, int* __restrict__ bsums){
  int r = blockIdx.x / SNB, b = blockIdx.x % SNB;
  const int* cnt = hist + r*NN;
  int t = threadIdx.x;
  int end = min((b+1)*SCH, NN);
  int s = 0;
  for(int j = b*SCH + t; j < end; j += 256) s += cnt[j];
  __shared__ int sh[4];
  for(int off=32; off; off>>=1) s += __shfl_down(s, off, 64);
  int lane = t & 63, w = t >> 6;
  if(lane==0) sh[w]=s;
  __syncthreads();
  if(t==0) bsums[blockIdx.x] = sh[0]+sh[1]+sh[2]+sh[3];
}

__global__ void __launch_bounds__(256)
k_scanwrite(const int* __restrict__ hist, const int* __restrict__ bsums,
            int* __restrict__ rowptr, int* __restrict__ cursor){
  int r = blockIdx.x / SNB, b = blockIdx.x % SNB;
  const int* cnt = hist + r*NN;
  int* rp  = rowptr + r*RPS;
  int* cur = cursor + r*NN;
  __shared__ int sh_off;
  __shared__ int wtot[4];
  int t = threadIdx.x;
  if(t==0){
    int o=0, tot=0;
    for(int i=0;i<SNB;i++){ int v=bsums[r*SNB+i]; if(i<b) o+=v; tot+=v; }
    sh_off=o;
    if(b==0) rp[NN]=tot;
  }
  int base = b*SCH + t*16;
  int v[16];
  bool full = (base+16 <= NN);
  if(full){
    int4 a0=((const int4*)cnt)[base/4+0];
    int4 a1=((const int4*)cnt)[base/4+1];
    int4 a2=((const int4*)cnt)[base/4+2];
    int4 a3=((const int4*)cnt)[base/4+3];
    v[0]=a0.x;v[1]=a0.y;v[2]=a0.z;v[3]=a0.w;
    v[4]=a1.x;v[5]=a1.y;v[6]=a1.z;v[7]=a1.w;
    v[8]=a2.x;v[9]=a2.y;v[10]=a2.z;v[11]=a2.w;
    v[12]=a3.x;v[13]=a3.y;v[14]=a3.z;v[15]=a3.w;
  } else {
    for(int j=0;j<16;j++){ int idx=base+j; v[j]=(idx<NN)?cnt[idx]:0; }
  }
  int loc=0;
  #pragma unroll
  for(int j=0;j<16;j++) loc += v[j];
  int lane = t & 63, w = t >> 6;
  int inc = loc;
  for(int off=1; off<64; off<<=1){ int n=__shfl_up(inc, off, 64); if(lane>=off) inc+=n; }
  if(lane==63) wtot[w]=inc;
  __syncthreads();
  int woff=0;
  for(int i=0;i<w;i++) woff += wtot[i];
  int run = sh_off + woff + inc - loc;
  if(full){
    int o[16];
    #pragma unroll
    for(int j=0;j<16;j++){ o[j]=run; run+=v[j]; }
    ((int4*)rp )[base/4+0]=make_int4(o[0],o[1],o[2],o[3]);
    ((int4*)rp )[base/4+1]=make_int4(o[4],o[5],o[6],o[7]);
    ((int4*)rp )[base/4+2]=make_int4(o[8],o[9],o[10],o[11]);
    ((int4*)rp )[base/4+3]=make_int4(o[12],o[13],o[14],o[15]);
    ((int4*)cur)[base/4+0]=make_int4(o[0],o[1],o[2],o[3]);
    ((int4*)cur)[base/4+1]=make_int4(o[4],o[5],o[6],o[7]);
    ((int4*)cur)[base/4+2]=make_int4(o[8],o[9],o[10],o[11]);
    ((int4*)cur)[base/4+3]=make_int4(o[12],o[13],o[14],o[15]);
  } else {
    for(int j=0;j<16;j++){
      int idx=base+j;
      if(idx<NN){ rp[idx]=run; cur[idx]=run; run+=v[j]; }
    }
  }
}

__global__ void k_scatter(const int* __restrict__ src, const int* __restrict__ dst,
                          int E, int* __restrict__ cursor, int* __restrict__ csr){
  int i = blockIdx.x*256 + threadIdx.x;
  if(i<E){ int pos = atomicAdd(&cursor[dst[i]],1); csr[pos]=src[i]; }
}

// ---------------- BN stats ----------------
__global__ void k_bnstats(const float* __restrict__ x, float* __restrict__ stats){
  __shared__ float sh[512];
  int t = threadIdx.x, col = t & 63, rg = t >> 6;
  float s=0.f, q=0.f;
  for(int row = blockIdx.x*4 + rg; row < NN; row += gridDim.x*4){
    float v = x[(size_t)row*64 + col]; s += v; q += v*v;
  }
  sh[t]=s; sh[256+t]=q; __syncthreads();
  if(rg==0){
    s = sh[col]+sh[64+col]+sh[128+col]+sh[192+col];
    q = sh[256+col]+sh[320+col]+sh[384+col]+sh[448+col];
    atomicAdd(&stats[col], s); atomicAdd(&stats[64+col], q);
  }
}

// ---------------- fold BN into weights; build Wal/War columns (parallel) ----
// wbuf layout (floats): [Whm 64*64][bias_hm 64] then per r: [W'_r 64*CREL][bias_r CREL]
// grid = 22 blocks: 0..11 = scaled-W cols (r = b>>2, 64-col chunk = b&3)
//                   12..17 = 24 waves, one per al/ar column
//                   18..21 = Whm, 16 d-values each (bias reduce over k stays in-block)
__global__ void __launch_bounds__(256)
k_prep2(const float* __restrict__ stats, const float* __restrict__ g,
        const float* __restrict__ be, const float* __restrict__ W,
        const float* __restrict__ al, const float* __restrict__ ar,
        const float* __restrict__ b, const float* __restrict__ rW,
        float* __restrict__ wbuf){
  __shared__ float scale[64], shift[64];
  __shared__ float red[256];
  int t = threadIdx.x;
  if(t<64){
    float mu  = stats[t]*(1.0f/NN);
    float var = stats[64+t]*(1.0f/NN) - mu*mu;
    float sc  = g[t]*rsqrtf(var + 1e-5f);
    scale[t]=sc; shift[t]=be[t]-mu*sc;
  }
  __syncthreads();
  int bid = blockIdx.x;
  if(bid < 12){
    int r = bid >> 2, c0 = (bid & 3)*64;
    float* Wo = wbuf + 4160 + r*(64*CREL + CREL);
    float* bo = Wo + 64*CREL;
    int c = c0 + (t & 63), kg = t >> 6;
    float bias = 0.f;
    #pragma unroll
    for(int j=0;j<16;j++){
      int k = kg*16 + j;
      float w = W[((size_t)(r*64+k))*256 + c];
      bias += shift[k]*w;
      Wo[k*CREL + c] = scale[k]*w;
    }
    red[t]=bias; __syncthreads();
    if(kg==0) bo[c] = red[t] + red[t+64] + red[t+128] + red[t+192];
  } else if(bid < 18){
    int wv = (bid-12)*4 + (t>>6);        // 0..23
    int r = wv >> 3, cc = wv & 7, h = cc & 3, k = t & 63;
    const float* av = ((cc>=4)?ar:al) + (r*HH+h)*64;
    const float* Wk = W + ((size_t)(r*64+k))*256 + h*64;
    float w=0.f;
    for(int d2=0; d2<64; d2++) w += Wk[d2]*av[d2];
    float* Wo = wbuf + 4160 + r*(64*CREL + CREL);
    Wo[k*CREL + 256 + cc] = scale[k]*w;
    float bp = shift[k]*w;
    for(int off=32; off; off>>=1) bp += __shfl_down(bp, off, 64);
    if(k==0) (Wo + 64*CREL)[256+cc] = bp;
  } else {
    int db = (bid-18)*16;
    int d = db + (t & 15), kg = t >> 4;  // 16 k-groups of 4
    float bias = 0.f;
    #pragma unroll
    for(int j=0;j<4;j++){
      int k = kg*4 + j;
      float w = 0.f;
      for(int r=0;r<3;r++)
        for(int h=0;h<HH;h++)
          w += rW[((size_t)(r*64+k))*256 + h*64 + d];
      w *= 0.25f;
      bias += shift[k]*w;
      wbuf[k*64+d] = scale[k]*w;
    }
    red[t]=bias; __syncthreads();
    if(t<16){
      float s=0.f;
      for(int i=t;i<256;i+=16) s += red[i];
      int dd = db + t;
      float bb=0.f;
      for(int r=0;r<3;r++) for(int h=0;h<HH;h++) bb += b[r*256 + h*64 + dd];
      wbuf[4096+dd] = s + 0.25f*bb;
    }
  }
}

// ---------------- matmul: [NN,64] @ [64,CREL] + bias ----------------
__global__ void __launch_bounds__(256)
k_matmulC(const float* __restrict__ A, const float* __restrict__ W,
          const float* __restrict__ bias, float* __restrict__ Y){
  __shared__ float xs[4096];
  int t = threadIdx.x;
  int row0 = blockIdx.x*64;
  for(int f=t; f<1024; f+=256){
    int r=f>>4; int row=row0+r;
    float4 v = (row<NN) ? ((const float4*)A)[(size_t)row*16 + (f&15)]
                        : make_float4(0.f,0.f,0.f,0.f);
    ((float4*)xs)[f]=v;
  }
  __syncthreads();
  int nrows = min(64, NN-row0);
  for(int c=t; c<CREL; c+=256){
    float wreg[64];
    #pragma unroll
    for(int k=0;k<64;k++) wreg[k]=W[k*CREL+c];
    float bs = bias[c];
    for(int r=0;r<nrows;r+=4){
      float a0=bs,a1=bs,a2=bs,a3=bs;
      #pragma unroll
      for(int k=0;k<64;k++){
        float w=wreg[k];
        a0 += xs[(r+0)*64+k]*w;
        a1 += xs[(r+1)*64+k]*w;
        a2 += xs[(r+2)*64+k]*w;
        a3 += xs[(r+3)*64+k]*w;
      }
      size_t base=(size_t)(row0+r)*CREL + c;
      if(row0+r+3 < NN){
        Y[base]=a0; Y[base+CREL]=a1; Y[base+2*CREL]=a2; Y[base+3*CREL]=a3;
      } else {
        if(row0+r   < NN) Y[base]=a0;
        if(row0+r+1 < NN) Y[base+CREL]=a1;
        if(row0+r+2 < NN) Y[base+2*CREL]=a2;
        if(row0+r+3 < NN) Y[base+3*CREL]=a3;
      }
    }
  }
}

// ---------------- matmul: [NN,64] @ [64,64] + bias (opt relu) ----------------
__global__ void __launch_bounds__(256)
k_matmul64(const float* __restrict__ A, const float* __restrict__ W,
           const float* __restrict__ bias, float* __restrict__ Y, int relu){
  __shared__ float xs[4096];
  int t = threadIdx.x;
  int row0 = blockIdx.x*64;
  for(int f=t; f<1024; f+=256){
    int r=f>>4; int row=row0+r;
    float4 v = (row<NN) ? ((const float4*)A)[(size_t)row*16 + (f&15)]
                        : make_float4(0.f,0.f,0.f,0.f);
    ((float4*)xs)[f]=v;
  }
  __syncthreads();
  int c = t & 63, rg = t >> 6;
  float wreg[64];
  #pragma unroll
  for(int k=0;k<64;k++) wreg[k]=W[k*64+c];
  float bs = bias[c];
  for(int r=rg*16; r<rg*16+16; r++){
    int row=row0+r; if(row>=NN) continue;
    float acc=bs;
    #pragma unroll
    for(int k=0;k<64;k++) acc += xs[r*64+k]*wreg[k];
    if(relu) acc=fmaxf(acc,0.f);
    Y[(size_t)row*64+c]=acc;
  }
}

// ---------------- per-node gather aggregation (one wave per dst node) --------
__global__ void __launch_bounds__(256)
k_agg(const float* __restrict__ Y, const int* __restrict__ rowptr,
      const int* __restrict__ csr, float* __restrict__ hacc){
  int wid  = (blockIdx.x*256 + threadIdx.x) >> 6;
  int lane = threadIdx.x & 63;
  if(wid>=NN) return;
  int beg = rowptr[wid], end = rowptr[wid+1];
  float out = 0.f;
  if(end>beg){
    const float* Yv = Y + (size_t)wid*CREL;
    float er0=Yv[260], er1=Yv[261], er2=Yv[262], er3=Yv[263];
    float m0=-1e30f,m1=-1e30f,m2=-1e30f,m3=-1e30f;
    float s0=0.f,s1=0.f,s2=0.f,s3=0.f;
    for(int i=beg;i<end;i++){
      int src = csr[i];
      const float* Ys = Y + (size_t)src*CREL + 256;
      float e0=Ys[0]+er0, e1=Ys[1]+er1, e2=Ys[2]+er2, e3=Ys[3]+er3;
      e0 = e0>0.f? e0 : 0.2f*e0;
      e1 = e1>0.f? e1 : 0.2f*e1;
      e2 = e2>0.f? e2 : 0.2f*e2;
      e3 = e3>0.f? e3 : 0.2f*e3;
      float n0=fmaxf(m0,e0); s0=s0*__expf(m0-n0)+__expf(e0-n0); m0=n0;
      float n1=fmaxf(m1,e1); s1=s1*__expf(m1-n1)+__expf(e1-n1); m1=n1;
      float n2=fmaxf(m2,e2); s2=s2*__expf(m2-n2)+__expf(e2-n2); m2=n2;
      float n3=fmaxf(m3,e3); s3=s3*__expf(m3-n3)+__expf(e3-n3); m3=n3;
    }
    float a0=0.f,a1=0.f,a2=0.f,a3=0.f;
    for(int i=beg;i<end;i++){
      int src = csr[i];
      const float* Ys = Y + (size_t)src*CREL;
      float e0=Ys[256]+er0, e1=Ys[257]+er1, e2=Ys[258]+er2, e3=Ys[259]+er3;
      e0 = e0>0.f? e0 : 0.2f*e0;
      e1 = e1>0.f? e1 : 0.2f*e1;
      e2 = e2>0.f? e2 : 0.2f*e2;
      e3 = e3>0.f? e3 : 0.2f*e3;
      float w0=__expf(e0-m0), w1=__expf(e1-m1), w2=__expf(e2-m2), w3=__expf(e3-m3);
      a0 += w0*Ys[lane];
      a1 += w1*Ys[64+lane];
      a2 += w2*Ys[128+lane];
      a3 += w3*Ys[192+lane];
    }
    out = 0.25f*(a0/s0 + a1/s1 + a2/s2 + a3/s3);
  }
  hacc[(size_t)wid*64 + lane] += out;
}

extern "C" void kernel_launch(void* const* d_in, const int* in_sizes, int n_in,
                              void* d_out, int out_size, void* d_ws, size_t ws_size,
                              hipStream_t stream){
  const float* x      =(const float*)d_in[0];
  const int* src_res  =(const int*)d_in[1];
  const int* dst_res  =(const int*)d_in[2];
  const int* src_seq  =(const int*)d_in[3];
  const int* dst_seq  =(const int*)d_in[4];
  const int* src_knn  =(const int*)d_in[5];
  const int* dst_knn  =(const int*)d_in[6];
  const float* W0 =(const float*)d_in[7];
  const float* al0=(const float*)d_in[8];
  const float* ar0=(const float*)d_in[9];
  const float* b0 =(const float*)d_in[10];
  const float* rW0=(const float*)d_in[11];
  const float* W1 =(const float*)d_in[12];
  const float* al1=(const float*)d_in[13];
  const float* ar1=(const float*)d_in[14];
  const float* b1 =(const float*)d_in[15];
  const float* rW1=(const float*)d_in[16];
  const float* fcW0=(const float*)d_in[17];
  const float* fcb0=(const float*)d_in[18];
  const float* fcW1=(const float*)d_in[19];
  const float* fcb1=(const float*)d_in[20];
  const float* g0 =(const float*)d_in[21];
  const float* be0=(const float*)d_in[22];
  const float* g1 =(const float*)d_in[23];
  const float* be1=(const float*)d_in[24];

  char* ws=(char*)d_ws;
  int*   hist   =(int*)  (ws+0);          // 3*NN ints = 600000 B
  float* stats0 =(float*)(ws+600000);     // 128 f
  float* stats1 =(float*)(ws+600512);     // 128 f
  int*   rowptr =(int*)  (ws+601024);     // 3*RPS ints
  int*   cursor =(int*)  (ws+1201088);    // 3*NN
  int*   csr    =(int*)  (ws+1801088);    // 900000
  float* wbuf   =(float*)(ws+5401088);    // 55640 f -> ends 5623648
  int*   bsums  =(int*)  (ws+5623648);    // 39 ints (gap before Y)
  float* Y      =(float*)(ws+5623808);    // NN*CREL f = 52.8 MB
  float* hacc   =(float*)(ws+58423808UL); // NN*64 f
  float* xbuf   =(float*)(ws+71223808UL); // NN*64 f

  hipMemsetAsync(ws, 0, 601024, stream);  // hist + both stats buffers

  k_hist<<<(E_RES+255)/256,256,0,stream>>>(dst_res,E_RES,hist);
  k_hist<<<(E_SEQ+255)/256,256,0,stream>>>(dst_seq,E_SEQ,hist+NN);
  k_hist<<<(E_KNN+255)/256,256,0,stream>>>(dst_knn,E_KNN,hist+2*NN);
  k_blocksum<<<3*SNB,256,0,stream>>>(hist,bsums);
  k_scanwrite<<<3*SNB,256,0,stream>>>(hist,bsums,rowptr,cursor);
  k_scatter<<<(E_RES+255)/256,256,0,stream>>>(src_res,dst_res,E_RES,cursor,csr);
  k_scatter<<<(E_SEQ+255)/256,256,0,stream>>>(src_seq,dst_seq,E_SEQ,cursor+NN,csr+E_RES);
  k_scatter<<<(E_KNN+255)/256,256,0,stream>>>(src_knn,dst_knn,E_KNN,cursor+2*NN,csr+E_RES+E_SEQ);

  const int MBLK=(NN+63)/64;   // 782
  // ---- layer 1 ----
  k_bnstats<<<256,256,0,stream>>>(x,stats0);
  k_prep2<<<22,256,0,stream>>>(stats0,g0,be0,W0,al0,ar0,b0,rW0,wbuf);
  k_matmul64<<<MBLK,256,0,stream>>>(x,wbuf,wbuf+4096,hacc,0);   // residual+bias, head-meaned
  for(int r=0;r<3;r++){
    float* Wr=wbuf+4160+r*(64*CREL+CREL);
    int csroff=(r==0)?0:(r==1)?E_RES:(E_RES+E_SEQ);
    k_matmulC<<<MBLK,256,0,stream>>>(x,Wr,Wr+64*CREL,Y);
    k_agg<<<(NN*64)/256,256,0,stream>>>(Y,rowptr+r*RPS,csr+csroff,hacc);
  }
  k_matmul64<<<MBLK,256,0,stream>>>(hacc,fcW0,fcb0,xbuf,1);
  // ---- layer 2 ----
  k_bnstats<<<256,256,0,stream>>>(xbuf,stats1);
  k_prep2<<<22,256,0,stream>>>(stats1,g1,be1,W1,al1,ar1,b1,rW1,wbuf);
  k_matmul64<<<MBLK,256,0,stream>>>(xbuf,wbuf,wbuf+4096,hacc,0);
  for(int r=0;r<3;r++){
    float* Wr=wbuf+4160+r*(64*CREL+CREL);
    int csroff=(r==0)?0:(r==1)?E_RES:(E_RES+E_SEQ);
    k_matmulC<<<MBLK,256,0,stream>>>(xbuf,Wr,Wr+64*CREL,Y);
    k_agg<<<(NN*64)/256,256,0,stream>>>(Y,rowptr+r*RPS,csr+csroff,hacc);
  }
  k_matmul64<<<MBLK,256,0,stream>>>(hacc,fcW1,fcb1,(float*)d_out,1);
}

// Round 4
// 1132.787 us; speedup vs baseline: 1.6860x; 1.0981x over previous
//
#include <hip/hip_runtime.h>
#include <math.h>

#define NN    50000
#define DD    64
#define HH    4
#define CREL  264          // 256 fs cols + 4 el + 4 er (weight matrix width)
#define E_RES 400000
#define E_SEQ 100000
#define E_KNN 400000
#define SCH   4096
#define SNB   ((NN + SCH - 1)/SCH)   // 13 chunks per relation
#define RPS   (NN + 4)               // rowptr stride (16B-aligned per relation)

// ---------------- CSR build ----------------
__global__ void k_hist(const int* __restrict__ dst, int E, int* __restrict__ cnt){
  int i = blockIdx.x*256 + threadIdx.x;
  if(i<E) atomicAdd(&cnt[dst[i]], 1);
}

__global__ void __launch_bounds__(256)
k_blocksum(const int* __restrict__ hist, int* __restrict__ bsums){
  int r = blockIdx.x / SNB, b = blockIdx.x % SNB;
  const int* cnt = hist + r*NN;
  int t = threadIdx.x;
  int end = min((b+1)*SCH, NN);
  int s = 0;
  for(int j = b*SCH + t; j < end; j += 256) s += cnt[j];
  __shared__ int sh[4];
  for(int off=32; off; off>>=1) s += __shfl_down(s, off, 64);
  int lane = t & 63, w = t >> 6;
  if(lane==0) sh[w]=s;
  __syncthreads();
  if(t==0) bsums[blockIdx.x] = sh[0]+sh[1]+sh[2]+sh[3];
}

__global__ void __launch_bounds__(256)
k_scanwrite(const int* __restrict__ hist, const int* __restrict__ bsums,
            int* __restrict__ rowptr, int* __restrict__ cursor){
  int r = blockIdx.x / SNB, b = blockIdx.x % SNB;
  const int* cnt = hist + r*NN;
  int* rp  = rowptr + r*RPS;
  int* cur = cursor + r*NN;
  __shared__ int sh_off;
  __shared__ int wtot[4];
  int t = threadIdx.x;
  if(t==0){
    int o=0, tot=0;
    for(int i=0;i<SNB;i++){ int v=bsums[r*SNB+i]; if(i<b) o+=v; tot+=v; }
    sh_off=o;
    if(b==0) rp[NN]=tot;
  }
  int base = b*SCH + t*16;
  int v[16];
  bool full = (base+16 <= NN);
  if(full){
    int4 a0=((const int4*)cnt)[base/4+0];
    int4 a1=((const int4*)cnt)[base/4+1];
    int4 a2=((const int4*)cnt)[base/4+2];
    int4 a3=((const int4*)cnt)[base/4+3];
    v[0]=a0.x;v[1]=a0.y;v[2]=a0.z;v[3]=a0.w;
    v[4]=a1.x;v[5]=a1.y;v[6]=a1.z;v[7]=a1.w;
    v[8]=a2.x;v[9]=a2.y;v[10]=a2.z;v[11]=a2.w;
    v[12]=a3.x;v[13]=a3.y;v[14]=a3.z;v[15]=a3.w;
  } else {
    for(int j=0;j<16;j++){ int idx=base+j; v[j]=(idx<NN)?cnt[idx]:0; }
  }
  int loc=0;
  #pragma unroll
  for(int j=0;j<16;j++) loc += v[j];
  int lane = t & 63, w = t >> 6;
  int inc = loc;
  for(int off=1; off<64; off<<=1){ int n=__shfl_up(inc, off, 64); if(lane>=off) inc+=n; }
  if(lane==63) wtot[w]=inc;
  __syncthreads();
  int woff=0;
  for(int i=0;i<w;i++) woff += wtot[i];
  int run = sh_off + woff + inc - loc;
  if(full){
    int o[16];
    #pragma unroll
    for(int j=0;j<16;j++){ o[j]=run; run+=v[j]; }
    ((int4*)rp )[base/4+0]=make_int4(o[0],o[1],o[2],o[3]);
    ((int4*)rp )[base/4+1]=make_int4(o[4],o[5],o[6],o[7]);
    ((int4*)rp )[base/4+2]=make_int4(o[8],o[9],o[10],o[11]);
    ((int4*)rp )[base/4+3]=make_int4(o[12],o[13],o[14],o[15]);
    ((int4*)cur)[base/4+0]=make_int4(o[0],o[1],o[2],o[3]);
    ((int4*)cur)[base/4+1]=make_int4(o[4],o[5],o[6],o[7]);
    ((int4*)cur)[base/4+2]=make_int4(o[8],o[9],o[10],o[11]);
    ((int4*)cur)[base/4+3]=make_int4(o[12],o[13],o[14],o[15]);
  } else {
    for(int j=0;j<16;j++){
      int idx=base+j;
      if(idx<NN){ rp[idx]=run; cur[idx]=run; run+=v[j]; }
    }
  }
}

__global__ void k_scatter(const int* __restrict__ src, const int* __restrict__ dst,
                          int E, int* __restrict__ cursor, int* __restrict__ csr){
  int i = blockIdx.x*256 + threadIdx.x;
  if(i<E){ int pos = atomicAdd(&cursor[dst[i]],1); csr[pos]=src[i]; }
}

// ---------------- BN stats ----------------
__global__ void k_bnstats(const float* __restrict__ x, float* __restrict__ stats){
  __shared__ float sh[512];
  int t = threadIdx.x, col = t & 63, rg = t >> 6;
  float s=0.f, q=0.f;
  for(int row = blockIdx.x*4 + rg; row < NN; row += gridDim.x*4){
    float v = x[(size_t)row*64 + col]; s += v; q += v*v;
  }
  sh[t]=s; sh[256+t]=q; __syncthreads();
  if(rg==0){
    s = sh[col]+sh[64+col]+sh[128+col]+sh[192+col];
    q = sh[256+col]+sh[320+col]+sh[384+col]+sh[448+col];
    atomicAdd(&stats[col], s); atomicAdd(&stats[64+col], q);
  }
}

// ---------------- fold BN into weights; build Wal/War columns (parallel) ----
__global__ void __launch_bounds__(256)
k_prep2(const float* __restrict__ stats, const float* __restrict__ g,
        const float* __restrict__ be, const float* __restrict__ W,
        const float* __restrict__ al, const float* __restrict__ ar,
        const float* __restrict__ b, const float* __restrict__ rW,
        float* __restrict__ wbuf){
  __shared__ float scale[64], shift[64];
  __shared__ float red[256];
  int t = threadIdx.x;
  if(t<64){
    float mu  = stats[t]*(1.0f/NN);
    float var = stats[64+t]*(1.0f/NN) - mu*mu;
    float sc  = g[t]*rsqrtf(var + 1e-5f);
    scale[t]=sc; shift[t]=be[t]-mu*sc;
  }
  __syncthreads();
  int bid = blockIdx.x;
  if(bid < 12){
    int r = bid >> 2, c0 = (bid & 3)*64;
    float* Wo = wbuf + 4160 + r*(64*CREL + CREL);
    float* bo = Wo + 64*CREL;
    int c = c0 + (t & 63), kg = t >> 6;
    float bias = 0.f;
    #pragma unroll
    for(int j=0;j<16;j++){
      int k = kg*16 + j;
      float w = W[((size_t)(r*64+k))*256 + c];
      bias += shift[k]*w;
      Wo[k*CREL + c] = scale[k]*w;
    }
    red[t]=bias; __syncthreads();
    if(kg==0) bo[c] = red[t] + red[t+64] + red[t+128] + red[t+192];
  } else if(bid < 18){
    int wv = (bid-12)*4 + (t>>6);        // 0..23
    int r = wv >> 3, cc = wv & 7, h = cc & 3, k = t & 63;
    const float* av = ((cc>=4)?ar:al) + (r*HH+h)*64;
    const float* Wk = W + ((size_t)(r*64+k))*256 + h*64;
    float w=0.f;
    for(int d2=0; d2<64; d2++) w += Wk[d2]*av[d2];
    float* Wo = wbuf + 4160 + r*(64*CREL + CREL);
    Wo[k*CREL + 256 + cc] = scale[k]*w;
    float bp = shift[k]*w;
    for(int off=32; off; off>>=1) bp += __shfl_down(bp, off, 64);
    if(k==0) (Wo + 64*CREL)[256+cc] = bp;
  } else {
    int db = (bid-18)*16;
    int d = db + (t & 15), kg = t >> 4;
    float bias = 0.f;
    #pragma unroll
    for(int j=0;j<4;j++){
      int k = kg*4 + j;
      float w = 0.f;
      for(int r=0;r<3;r++)
        for(int h=0;h<HH;h++)
          w += rW[((size_t)(r*64+k))*256 + h*64 + d];
      w *= 0.25f;
      bias += shift[k]*w;
      wbuf[k*64+d] = scale[k]*w;
    }
    red[t]=bias; __syncthreads();
    if(t<16){
      float s=0.f;
      for(int i=t;i<256;i+=16) s += red[i];
      int dd = db + t;
      float bb=0.f;
      for(int r=0;r<3;r++) for(int h=0;h<HH;h++) bb += b[r*256 + h*64 + dd];
      wbuf[4096+dd] = s + 0.25f*bb;
    }
  }
}

// ---------------- matmul: [NN,64] @ [64,CREL]; fs -> Y[NN,256], el/er -> EL[NN,8]
__global__ void __launch_bounds__(256)
k_matmulC(const float* __restrict__ A, const float* __restrict__ W,
          const float* __restrict__ bias, float* __restrict__ Y,
          float* __restrict__ EL){
  __shared__ float xs[4096];
  int t = threadIdx.x;
  int row0 = blockIdx.x*64;
  for(int f=t; f<1024; f+=256){
    int r=f>>4; int row=row0+r;
    float4 v = (row<NN) ? ((const float4*)A)[(size_t)row*16 + (f&15)]
                        : make_float4(0.f,0.f,0.f,0.f);
    ((float4*)xs)[f]=v;
  }
  __syncthreads();
  int nrows = min(64, NN-row0);
  for(int c=t; c<CREL; c+=256){
    float wreg[64];
    #pragma unroll
    for(int k=0;k<64;k++) wreg[k]=W[k*CREL+c];
    float bs = bias[c];
    for(int r=0;r<nrows;r+=4){
      float a0=bs,a1=bs,a2=bs,a3=bs;
      #pragma unroll
      for(int k=0;k<64;k++){
        float w=wreg[k];
        a0 += xs[(r+0)*64+k]*w;
        a1 += xs[(r+1)*64+k]*w;
        a2 += xs[(r+2)*64+k]*w;
        a3 += xs[(r+3)*64+k]*w;
      }
      int row=row0+r;
      if(c<256){
        size_t base=(size_t)row*256 + c;
        if(row+3 < NN){
          Y[base]=a0; Y[base+256]=a1; Y[base+512]=a2; Y[base+768]=a3;
        } else {
          if(row   < NN) Y[base]=a0;
          if(row+1 < NN) Y[base+256]=a1;
          if(row+2 < NN) Y[base+512]=a2;
          if(row+3 < NN) Y[base+768]=a3;
        }
      } else {
        size_t base=(size_t)row*8 + (c-256);
        if(row+3 < NN){
          EL[base]=a0; EL[base+8]=a1; EL[base+16]=a2; EL[base+24]=a3;
        } else {
          if(row   < NN) EL[base]=a0;
          if(row+1 < NN) EL[base+8]=a1;
          if(row+2 < NN) EL[base+16]=a2;
          if(row+3 < NN) EL[base+24]=a3;
        }
      }
    }
  }
}

// ---------------- matmul: [NN,64] @ [64,64] + bias (opt relu) ----------------
__global__ void __launch_bounds__(256)
k_matmul64(const float* __restrict__ A, const float* __restrict__ W,
           const float* __restrict__ bias, float* __restrict__ Y, int relu){
  __shared__ float xs[4096];
  int t = threadIdx.x;
  int row0 = blockIdx.x*64;
  for(int f=t; f<1024; f+=256){
    int r=f>>4; int row=row0+r;
    float4 v = (row<NN) ? ((const float4*)A)[(size_t)row*16 + (f&15)]
                        : make_float4(0.f,0.f,0.f,0.f);
    ((float4*)xs)[f]=v;
  }
  __syncthreads();
  int c = t & 63, rg = t >> 6;
  float wreg[64];
  #pragma unroll
  for(int k=0;k<64;k++) wreg[k]=W[k*64+c];
  float bs = bias[c];
  for(int r=rg*16; r<rg*16+16; r++){
    int row=row0+r; if(row>=NN) continue;
    float acc=bs;
    #pragma unroll
    for(int k=0;k<64;k++) acc += xs[r*64+k]*wreg[k];
    if(relu) acc=fmaxf(acc,0.f);
    Y[(size_t)row*64+c]=acc;
  }
}

// ---------------- edge coefficients: one THREAD per dst node ----------------
// EL[n] = {el0..el3, er0..er3}. coef[i] <- normalized alpha quad per edge.
__global__ void __launch_bounds__(256)
k_edgecoef(const float* __restrict__ EL, const int* __restrict__ rowptr,
           const int* __restrict__ csr, float4* __restrict__ coef){
  int n = blockIdx.x*256 + threadIdx.x;
  if(n>=NN) return;
  int beg = rowptr[n], end = rowptr[n+1];
  if(end<=beg) return;
  const float4 er = ((const float4*)EL)[n*2+1];
  float m0=-1e30f,m1=-1e30f,m2=-1e30f,m3=-1e30f;
  float s0=0.f,s1=0.f,s2=0.f,s3=0.f;
  for(int i=beg;i<end;i++){
    int src = csr[i];
    float4 el = ((const float4*)EL)[src*2];
    float e0=el.x+er.x, e1=el.y+er.y, e2=el.z+er.z, e3=el.w+er.w;
    e0 = e0>0.f? e0 : 0.2f*e0;
    e1 = e1>0.f? e1 : 0.2f*e1;
    e2 = e2>0.f? e2 : 0.2f*e2;
    e3 = e3>0.f? e3 : 0.2f*e3;
    float n0=fmaxf(m0,e0); s0=s0*__expf(m0-n0)+__expf(e0-n0); m0=n0;
    float n1=fmaxf(m1,e1); s1=s1*__expf(m1-n1)+__expf(e1-n1); m1=n1;
    float n2=fmaxf(m2,e2); s2=s2*__expf(m2-n2)+__expf(e2-n2); m2=n2;
    float n3=fmaxf(m3,e3); s3=s3*__expf(m3-n3)+__expf(e3-n3); m3=n3;
    coef[i] = make_float4(e0,e1,e2,e3);
  }
  float r0=1.f/s0, r1=1.f/s1, r2=1.f/s2, r3=1.f/s3;
  for(int i=beg;i<end;i++){
    float4 e = coef[i];
    coef[i] = make_float4(__expf(e.x-m0)*r0, __expf(e.y-m1)*r1,
                          __expf(e.z-m2)*r2, __expf(e.w-m3)*r3);
  }
}

// ---------------- weighted gather: one WAVE per dst node --------------------
__global__ void __launch_bounds__(256)
k_agg2(const float* __restrict__ Y, const int* __restrict__ rowptr,
       const int* __restrict__ csr, const float4* __restrict__ coef,
       float* __restrict__ hacc){
  int wid  = (blockIdx.x*256 + threadIdx.x) >> 6;
  int lane = threadIdx.x & 63;
  if(wid>=NN) return;
  int beg = rowptr[wid], end = rowptr[wid+1];
  if(end<=beg) return;
  float a = 0.f;
  for(int i=beg;i<end;i++){
    int src = csr[i];
    float4 al4 = coef[i];
    const float* Ys = Y + ((size_t)src<<8);
    a += al4.x*Ys[lane] + al4.y*Ys[64+lane] + al4.z*Ys[128+lane] + al4.w*Ys[192+lane];
  }
  hacc[(size_t)wid*64 + lane] += 0.25f*a;
}

extern "C" void kernel_launch(void* const* d_in, const int* in_sizes, int n_in,
                              void* d_out, int out_size, void* d_ws, size_t ws_size,
                              hipStream_t stream){
  const float* x      =(const float*)d_in[0];
  const int* src_res  =(const int*)d_in[1];
  const int* dst_res  =(const int*)d_in[2];
  const int* src_seq  =(const int*)d_in[3];
  const int* dst_seq  =(const int*)d_in[4];
  const int* src_knn  =(const int*)d_in[5];
  const int* dst_knn  =(const int*)d_in[6];
  const float* W0 =(const float*)d_in[7];
  const float* al0=(const float*)d_in[8];
  const float* ar0=(const float*)d_in[9];
  const float* b0 =(const float*)d_in[10];
  const float* rW0=(const float*)d_in[11];
  const float* W1 =(const float*)d_in[12];
  const float* al1=(const float*)d_in[13];
  const float* ar1=(const float*)d_in[14];
  const float* b1 =(const float*)d_in[15];
  const float* rW1=(const float*)d_in[16];
  const float* fcW0=(const float*)d_in[17];
  const float* fcb0=(const float*)d_in[18];
  const float* fcW1=(const float*)d_in[19];
  const float* fcb1=(const float*)d_in[20];
  const float* g0 =(const float*)d_in[21];
  const float* be0=(const float*)d_in[22];
  const float* g1 =(const float*)d_in[23];
  const float* be1=(const float*)d_in[24];

  char* ws=(char*)d_ws;
  int*   hist   =(int*)  (ws+0);          // 3*NN ints
  float* stats0 =(float*)(ws+600000);
  float* stats1 =(float*)(ws+600512);
  int*   rowptr =(int*)  (ws+601024);     // 3*RPS ints
  int*   cursor =(int*)  (ws+1201088);
  int*   csr    =(int*)  (ws+1801088);    // 900000 ints
  float* wbuf   =(float*)(ws+5401088);
  int*   bsums  =(int*)  (ws+5623648);
  float* Y      =(float*)(ws+5623808);    // NN*256 f = 51.2 MB
  float* hacc   =(float*)(ws+58423808UL); // NN*64 f
  float* xbuf   =(float*)(ws+71223808UL); // NN*64 f
  float* EL     =(float*)(ws+84023808UL); // NN*8 f = 1.6 MB
  float4* coef  =(float4*)(ws+85623808UL);// 400000 float4 = 6.4 MB

  hipMemsetAsync(ws, 0, 601024, stream);  // hist + both stats buffers

  k_hist<<<(E_RES+255)/256,256,0,stream>>>(dst_res,E_RES,hist);
  k_hist<<<(E_SEQ+255)/256,256,0,stream>>>(dst_seq,E_SEQ,hist+NN);
  k_hist<<<(E_KNN+255)/256,256,0,stream>>>(dst_knn,E_KNN,hist+2*NN);
  k_blocksum<<<3*SNB,256,0,stream>>>(hist,bsums);
  k_scanwrite<<<3*SNB,256,0,stream>>>(hist,bsums,rowptr,cursor);
  k_scatter<<<(E_RES+255)/256,256,0,stream>>>(src_res,dst_res,E_RES,cursor,csr);
  k_scatter<<<(E_SEQ+255)/256,256,0,stream>>>(src_seq,dst_seq,E_SEQ,cursor+NN,csr+E_RES);
  k_scatter<<<(E_KNN+255)/256,256,0,stream>>>(src_knn,dst_knn,E_KNN,cursor+2*NN,csr+E_RES+E_SEQ);

  const int MBLK=(NN+63)/64;   // 782
  const int NBLK=(NN+255)/256; // 196
  // ---- layer 1 ----
  k_bnstats<<<256,256,0,stream>>>(x,stats0);
  k_prep2<<<22,256,0,stream>>>(stats0,g0,be0,W0,al0,ar0,b0,rW0,wbuf);
  k_matmul64<<<MBLK,256,0,stream>>>(x,wbuf,wbuf+4096,hacc,0);   // residual+bias, head-meaned
  for(int r=0;r<3;r++){
    float* Wr=wbuf+4160+r*(64*CREL+CREL);
    int csroff=(r==0)?0:(r==1)?E_RES:(E_RES+E_SEQ);
    k_matmulC<<<MBLK,256,0,stream>>>(x,Wr,Wr+64*CREL,Y,EL);
    k_edgecoef<<<NBLK,256,0,stream>>>(EL,rowptr+r*RPS,csr+csroff,coef);
    k_agg2<<<(NN*64)/256,256,0,stream>>>(Y,rowptr+r*RPS,csr+csroff,coef,hacc);
  }
  k_matmul64<<<MBLK,256,0,stream>>>(hacc,fcW0,fcb0,xbuf,1);
  // ---- layer 2 ----
  k_bnstats<<<256,256,0,stream>>>(xbuf,stats1);
  k_prep2<<<22,256,0,stream>>>(stats1,g1,be1,W1,al1,ar1,b1,rW1,wbuf);
  k_matmul64<<<MBLK,256,0,stream>>>(xbuf,wbuf,wbuf+4096,hacc,0);
  for(int r=0;r<3;r++){
    float* Wr=wbuf+4160+r*(64*CREL+CREL);
    int csroff=(r==0)?0:(r==1)?E_RES:(E_RES+E_SEQ);
    k_matmulC<<<MBLK,256,0,stream>>>(xbuf,Wr,Wr+64*CREL,Y,EL);
    k_edgecoef<<<NBLK,256,0,stream>>>(EL,rowptr+r*RPS,csr+csroff,coef);
    k_agg2<<<(NN*64)/256,256,0,stream>>>(Y,rowptr+r*RPS,csr+csroff,coef,hacc);
  }
  k_matmul64<<<MBLK,256,0,stream>>>(hacc,fcW1,fcb1,(float*)d_out,1);
}

// Round 5
// 881.729 us; speedup vs baseline: 2.1661x; 1.2847x over previous
//
#include <hip/hip_runtime.h>
#include <math.h>

#define NN    50000
#define DD    64
#define HH    4
#define E_RES 400000
#define E_SEQ 100000
#define E_KNN 400000
#define SCH   4096
#define SNB   ((NN + SCH - 1)/SCH)   // 13 chunks per relation
#define RPS   (NN + 4)               // rowptr stride (16B-aligned per relation)
#define WRSTRIDE 8968                // floats per relation in wbuf

typedef __attribute__((ext_vector_type(8))) short short8;
typedef __attribute__((ext_vector_type(4))) float floatx4;

__device__ inline unsigned short f2bf(float f){
  union{float f; unsigned u;} v; v.f=f;
  unsigned r = v.u + 0x7FFF + ((v.u>>16)&1);
  return (unsigned short)(r>>16);
}
__device__ inline float bf2f(unsigned short u){
  union{unsigned u; float f;} v; v.u=(unsigned)u<<16; return v.f;
}

// ---------------- CSR build ----------------
__global__ void k_hist(const int* __restrict__ dst, int E, int* __restrict__ cnt){
  int i = blockIdx.x*256 + threadIdx.x;
  if(i<E) atomicAdd(&cnt[dst[i]], 1);
}

__global__ void __launch_bounds__(256)
k_blocksum(const int* __restrict__ hist, int* __restrict__ bsums){
  int r = blockIdx.x / SNB, b = blockIdx.x % SNB;
  const int* cnt = hist + r*NN;
  int t = threadIdx.x;
  int end = min((b+1)*SCH, NN);
  int s = 0;
  for(int j = b*SCH + t; j < end; j += 256) s += cnt[j];
  __shared__ int sh[4];
  for(int off=32; off; off>>=1) s += __shfl_down(s, off, 64);
  int lane = t & 63, w = t >> 6;
  if(lane==0) sh[w]=s;
  __syncthreads();
  if(t==0) bsums[blockIdx.x] = sh[0]+sh[1]+sh[2]+sh[3];
}

__global__ void __launch_bounds__(256)
k_scanwrite(const int* __restrict__ hist, const int* __restrict__ bsums,
            int* __restrict__ rowptr, int* __restrict__ cursor){
  int r = blockIdx.x / SNB, b = blockIdx.x % SNB;
  const int* cnt = hist + r*NN;
  int* rp  = rowptr + r*RPS;
  int* cur = cursor + r*NN;
  __shared__ int sh_off;
  __shared__ int wtot[4];
  int t = threadIdx.x;
  if(t==0){
    int o=0, tot=0;
    for(int i=0;i<SNB;i++){ int v=bsums[r*SNB+i]; if(i<b) o+=v; tot+=v; }
    sh_off=o;
    if(b==0) rp[NN]=tot;
  }
  int base = b*SCH + t*16;
  int v[16];
  bool full = (base+16 <= NN);
  if(full){
    int4 a0=((const int4*)cnt)[base/4+0];
    int4 a1=((const int4*)cnt)[base/4+1];
    int4 a2=((const int4*)cnt)[base/4+2];
    int4 a3=((const int4*)cnt)[base/4+3];
    v[0]=a0.x;v[1]=a0.y;v[2]=a0.z;v[3]=a0.w;
    v[4]=a1.x;v[5]=a1.y;v[6]=a1.z;v[7]=a1.w;
    v[8]=a2.x;v[9]=a2.y;v[10]=a2.z;v[11]=a2.w;
    v[12]=a3.x;v[13]=a3.y;v[14]=a3.z;v[15]=a3.w;
  } else {
    for(int j=0;j<16;j++){ int idx=base+j; v[j]=(idx<NN)?cnt[idx]:0; }
  }
  int loc=0;
  #pragma unroll
  for(int j=0;j<16;j++) loc += v[j];
  int lane = t & 63, w = t >> 6;
  int inc = loc;
  for(int off=1; off<64; off<<=1){ int n=__shfl_up(inc, off, 64); if(lane>=off) inc+=n; }
  if(lane==63) wtot[w]=inc;
  __syncthreads();
  int woff=0;
  for(int i=0;i<w;i++) woff += wtot[i];
  int run = sh_off + woff + inc - loc;
  if(full){
    int o[16];
    #pragma unroll
    for(int j=0;j<16;j++){ o[j]=run; run+=v[j]; }
    ((int4*)rp )[base/4+0]=make_int4(o[0],o[1],o[2],o[3]);
    ((int4*)rp )[base/4+1]=make_int4(o[4],o[5],o[6],o[7]);
    ((int4*)rp )[base/4+2]=make_int4(o[8],o[9],o[10],o[11]);
    ((int4*)rp )[base/4+3]=make_int4(o[12],o[13],o[14],o[15]);
    ((int4*)cur)[base/4+0]=make_int4(o[0],o[1],o[2],o[3]);
    ((int4*)cur)[base/4+1]=make_int4(o[4],o[5],o[6],o[7]);
    ((int4*)cur)[base/4+2]=make_int4(o[8],o[9],o[10],o[11]);
    ((int4*)cur)[base/4+3]=make_int4(o[12],o[13],o[14],o[15]);
  } else {
    for(int j=0;j<16;j++){
      int idx=base+j;
      if(idx<NN){ rp[idx]=run; cur[idx]=run; run+=v[j]; }
    }
  }
}

__global__ void k_scatter(const int* __restrict__ src, const int* __restrict__ dst,
                          int E, int* __restrict__ cursor, int* __restrict__ csr){
  int i = blockIdx.x*256 + threadIdx.x;
  if(i<E){ int pos = atomicAdd(&cursor[dst[i]],1); csr[pos]=src[i]; }
}

// ---------------- BN stats ----------------
__global__ void k_bnstats(const float* __restrict__ x, float* __restrict__ stats){
  __shared__ float sh[512];
  int t = threadIdx.x, col = t & 63, rg = t >> 6;
  float s=0.f, q=0.f;
  for(int row = blockIdx.x*4 + rg; row < NN; row += gridDim.x*4){
    float v = x[(size_t)row*64 + col]; s += v; q += v*v;
  }
  sh[t]=s; sh[256+t]=q; __syncthreads();
  if(rg==0){
    s = sh[col]+sh[64+col]+sh[128+col]+sh[192+col];
    q = sh[256+col]+sh[320+col]+sh[384+col]+sh[448+col];
    atomicAdd(&stats[col], s); atomicAdd(&stats[64+col], q);
  }
}

// ---------------- fold BN into weights (parallel) ---------------------------
// wbuf layout (floats): [Whm 64*64][bias_hm 64] then per r (WRSTRIDE floats):
//   Wt_bf (ushort[256*64], c-major k-contig, col perm c=d*4+h) = 8192 f-slots
//   biasC f32[256] (permuted), Wel f32[8*64] ([cc][k], cc=0..3 el,4..7 er), biasE f32[8]
__global__ void __launch_bounds__(256)
k_prep2(const float* __restrict__ stats, const float* __restrict__ g,
        const float* __restrict__ be, const float* __restrict__ W,
        const float* __restrict__ al, const float* __restrict__ ar,
        const float* __restrict__ b, const float* __restrict__ rW,
        float* __restrict__ wbuf){
  __shared__ float scale[64], shift[64];
  __shared__ float red[256];
  int t = threadIdx.x;
  if(t<64){
    float mu  = stats[t]*(1.0f/NN);
    float var = stats[64+t]*(1.0f/NN) - mu*mu;
    float sc  = g[t]*rsqrtf(var + 1e-5f);
    scale[t]=sc; shift[t]=be[t]-mu*sc;
  }
  __syncthreads();
  int bid = blockIdx.x;
  if(bid < 12){
    int r = bid >> 2, c0 = (bid & 3)*64;
    float* fr = wbuf + 4160 + r*WRSTRIDE;
    unsigned short* Wt = (unsigned short*)fr;
    float* bo = fr + 8192;
    int cl = c0 + (t & 63), kg = t >> 6;
    int h = cl >> 6, d = cl & 63, cp = d*4 + h;
    float bias = 0.f;
    #pragma unroll
    for(int j=0;j<16;j++){
      int k = kg*16 + j;
      float w = W[((size_t)(r*64+k))*256 + cl];
      bias += shift[k]*w;
      Wt[cp*64 + k] = f2bf(scale[k]*w);
    }
    red[t]=bias; __syncthreads();
    if(kg==0) bo[cp] = red[t] + red[t+64] + red[t+128] + red[t+192];
  } else if(bid < 18){
    int wv = (bid-12)*4 + (t>>6);        // 0..23
    int r = wv >> 3, cc = wv & 7, h = cc & 3, k = t & 63;
    const float* av = ((cc>=4)?ar:al) + (r*HH+h)*64;
    const float* Wk = W + ((size_t)(r*64+k))*256 + h*64;
    float w=0.f;
    for(int d2=0; d2<64; d2++) w += Wk[d2]*av[d2];
    float* fr = wbuf + 4160 + r*WRSTRIDE;
    (fr + 8448)[cc*64 + k] = scale[k]*w;   // Wel
    float bp = shift[k]*w;
    for(int off=32; off; off>>=1) bp += __shfl_down(bp, off, 64);
    if(k==0) (fr + 8960)[cc] = bp;         // biasE
  } else {
    int db = (bid-18)*16;
    int d = db + (t & 15), kg = t >> 4;
    float bias = 0.f;
    #pragma unroll
    for(int j=0;j<4;j++){
      int k = kg*4 + j;
      float w = 0.f;
      for(int r=0;r<3;r++)
        for(int h=0;h<HH;h++)
          w += rW[((size_t)(r*64+k))*256 + h*64 + d];
      w *= 0.25f;
      bias += shift[k]*w;
      wbuf[k*64+d] = scale[k]*w;
    }
    red[t]=bias; __syncthreads();
    if(t<16){
      float s=0.f;
      for(int i=t;i<256;i+=16) s += red[i];
      int dd = db + t;
      float bb=0.f;
      for(int r=0;r<3;r++) for(int h=0;h<HH;h++) bb += b[r*256 + h*64 + dd];
      wbuf[4096+dd] = s + 0.25f*bb;
    }
  }
}

// ---------------- cast activations f32 -> bf16 ------------------------------
__global__ void __launch_bounds__(256)
k_cast(const float* __restrict__ X, unsigned short* __restrict__ out){
  int i = blockIdx.x*256 + threadIdx.x;   // one float4 per thread
  float4 v = ((const float4*)X)[i];
  ushort4 o;
  o.x=f2bf(v.x); o.y=f2bf(v.y); o.z=f2bf(v.z); o.w=f2bf(v.w);
  ((ushort4*)out)[i]=o;
}

// ---------------- MFMA matmul: Ybf[N,256] = Abf[N,64] @ W + bias ------------
__global__ void __launch_bounds__(256)
k_mfmaC(const unsigned short* __restrict__ Abf, const float* __restrict__ fr,
        unsigned short* __restrict__ Ybf){
  const unsigned short* Wt = (const unsigned short*)fr;
  const float* biasC = fr + 8192;
  int t = threadIdx.x;
  int wv = t>>6, lane = t&63;
  int m = lane&15, kq = lane>>4;       // kq=0..3
  int row = blockIdx.x*64 + wv*16 + m;
  int rc = row < NN ? row : NN-1;
  short8 a0 = *(const short8*)(Abf + (size_t)rc*64 + kq*8);
  short8 a1 = *(const short8*)(Abf + (size_t)rc*64 + 32 + kq*8);
  int orow = blockIdx.x*64 + wv*16 + kq*4;
  for(int ct=0; ct<16; ct++){
    int col = ct*16 + m;
    const unsigned short* wp = Wt + (size_t)col*64 + kq*8;
    short8 b0 = *(const short8*)(wp);
    short8 b1 = *(const short8*)(wp + 32);
    floatx4 acc = {0.f,0.f,0.f,0.f};
    acc = __builtin_amdgcn_mfma_f32_16x16x32_bf16(a0, b0, acc, 0,0,0);
    acc = __builtin_amdgcn_mfma_f32_16x16x32_bf16(a1, b1, acc, 0,0,0);
    float bs = biasC[col];
    #pragma unroll
    for(int ri=0; ri<4; ri++){
      int ro = orow + ri;
      if(ro < NN) Ybf[(size_t)ro*256 + col] = f2bf(acc[ri] + bs);
    }
  }
}

// ---------------- el/er: EL[N,8] = A[N,64] @ Wel (f32, exact) ---------------
__global__ void __launch_bounds__(256)
k_el(const float* __restrict__ A, const float* __restrict__ fr,
     float* __restrict__ EL){
  const float* Wel = fr + 8448;
  const float* biasE = fr + 8960;
  __shared__ float sw[512];
  __shared__ float sb[8];
  int t = threadIdx.x;
  sw[t]=Wel[t]; sw[256+t]=Wel[256+t];
  if(t<8) sb[t]=biasE[t];
  __syncthreads();
  int n = blockIdx.x*256 + t;
  if(n>=NN) return;
  float acc[8];
  #pragma unroll
  for(int c=0;c<8;c++) acc[c]=sb[c];
  const float4* Ar = (const float4*)(A + (size_t)n*64);
  #pragma unroll
  for(int kq=0;kq<16;kq++){
    float4 a = Ar[kq];
    #pragma unroll
    for(int c=0;c<8;c++){
      const float* w = sw + c*64 + kq*4;
      acc[c] += a.x*w[0] + a.y*w[1] + a.z*w[2] + a.w*w[3];
    }
  }
  ((float4*)EL)[n*2]   = make_float4(acc[0],acc[1],acc[2],acc[3]);
  ((float4*)EL)[n*2+1] = make_float4(acc[4],acc[5],acc[6],acc[7]);
}

// ---------------- matmul: [NN,64] @ [64,64] + bias (opt relu) ----------------
__global__ void __launch_bounds__(256)
k_matmul64(const float* __restrict__ A, const float* __restrict__ W,
           const float* __restrict__ bias, float* __restrict__ Y, int relu){
  __shared__ float xs[4096];
  int t = threadIdx.x;
  int row0 = blockIdx.x*64;
  for(int f=t; f<1024; f+=256){
    int r=f>>4; int row=row0+r;
    float4 v = (row<NN) ? ((const float4*)A)[(size_t)row*16 + (f&15)]
                        : make_float4(0.f,0.f,0.f,0.f);
    ((float4*)xs)[f]=v;
  }
  __syncthreads();
  int c = t & 63, rg = t >> 6;
  float wreg[64];
  #pragma unroll
  for(int k=0;k<64;k++) wreg[k]=W[k*64+c];
  float bs = bias[c];
  for(int r=rg*16; r<rg*16+16; r++){
    int row=row0+r; if(row>=NN) continue;
    float acc=bs;
    #pragma unroll
    for(int k=0;k<64;k++) acc += xs[r*64+k]*wreg[k];
    if(relu) acc=fmaxf(acc,0.f);
    Y[(size_t)row*64+c]=acc;
  }
}

// ---------------- edge coefficients: one THREAD per dst node ----------------
__global__ void __launch_bounds__(256)
k_edgecoef(const float* __restrict__ EL, const int* __restrict__ rowptr,
           const int* __restrict__ csr, float4* __restrict__ coef){
  int n = blockIdx.x*256 + threadIdx.x;
  if(n>=NN) return;
  int beg = rowptr[n], end = rowptr[n+1];
  if(end<=beg) return;
  const float4 er = ((const float4*)EL)[n*2+1];
  float m0=-1e30f,m1=-1e30f,m2=-1e30f,m3=-1e30f;
  float s0=0.f,s1=0.f,s2=0.f,s3=0.f;
  for(int i=beg;i<end;i++){
    int src = csr[i];
    float4 el = ((const float4*)EL)[src*2];
    float e0=el.x+er.x, e1=el.y+er.y, e2=el.z+er.z, e3=el.w+er.w;
    e0 = e0>0.f? e0 : 0.2f*e0;
    e1 = e1>0.f? e1 : 0.2f*e1;
    e2 = e2>0.f? e2 : 0.2f*e2;
    e3 = e3>0.f? e3 : 0.2f*e3;
    float n0=fmaxf(m0,e0); s0=s0*__expf(m0-n0)+__expf(e0-n0); m0=n0;
    float n1=fmaxf(m1,e1); s1=s1*__expf(m1-n1)+__expf(e1-n1); m1=n1;
    float n2=fmaxf(m2,e2); s2=s2*__expf(m2-n2)+__expf(e2-n2); m2=n2;
    float n3=fmaxf(m3,e3); s3=s3*__expf(m3-n3)+__expf(e3-n3); m3=n3;
    coef[i] = make_float4(e0,e1,e2,e3);
  }
  float r0=1.f/s0, r1=1.f/s1, r2=1.f/s2, r3=1.f/s3;
  for(int i=beg;i<end;i++){
    float4 e = coef[i];
    coef[i] = make_float4(__expf(e.x-m0)*r0, __expf(e.y-m1)*r1,
                          __expf(e.z-m2)*r2, __expf(e.w-m3)*r3);
  }
}

// ---------------- weighted gather (bf16 Y): one WAVE per dst node -----------
__global__ void __launch_bounds__(256)
k_agg2(const unsigned short* __restrict__ Ybf, const int* __restrict__ rowptr,
       const int* __restrict__ csr, const float4* __restrict__ coef,
       float* __restrict__ hacc){
  int wid  = (blockIdx.x*256 + threadIdx.x) >> 6;
  int lane = threadIdx.x & 63;
  if(wid>=NN) return;
  int beg = rowptr[wid], end = rowptr[wid+1];
  if(end<=beg) return;
  float a = 0.f;
  for(int i=beg;i<end;i++){
    int src = csr[i];
    float4 c = coef[i];
    ushort4 yv = *(const ushort4*)(Ybf + ((size_t)src<<8) + lane*4);
    a += c.x*bf2f(yv.x) + c.y*bf2f(yv.y) + c.z*bf2f(yv.z) + c.w*bf2f(yv.w);
  }
  hacc[(size_t)wid*64 + lane] += 0.25f*a;
}

extern "C" void kernel_launch(void* const* d_in, const int* in_sizes, int n_in,
                              void* d_out, int out_size, void* d_ws, size_t ws_size,
                              hipStream_t stream){
  const float* x      =(const float*)d_in[0];
  const int* src_res  =(const int*)d_in[1];
  const int* dst_res  =(const int*)d_in[2];
  const int* src_seq  =(const int*)d_in[3];
  const int* dst_seq  =(const int*)d_in[4];
  const int* src_knn  =(const int*)d_in[5];
  const int* dst_knn  =(const int*)d_in[6];
  const float* W0 =(const float*)d_in[7];
  const float* al0=(const float*)d_in[8];
  const float* ar0=(const float*)d_in[9];
  const float* b0 =(const float*)d_in[10];
  const float* rW0=(const float*)d_in[11];
  const float* W1 =(const float*)d_in[12];
  const float* al1=(const float*)d_in[13];
  const float* ar1=(const float*)d_in[14];
  const float* b1 =(const float*)d_in[15];
  const float* rW1=(const float*)d_in[16];
  const float* fcW0=(const float*)d_in[17];
  const float* fcb0=(const float*)d_in[18];
  const float* fcW1=(const float*)d_in[19];
  const float* fcb1=(const float*)d_in[20];
  const float* g0 =(const float*)d_in[21];
  const float* be0=(const float*)d_in[22];
  const float* g1 =(const float*)d_in[23];
  const float* be1=(const float*)d_in[24];

  char* ws=(char*)d_ws;
  int*   hist   =(int*)  (ws+0);               // 3*NN ints
  float* stats0 =(float*)(ws+600000);
  float* stats1 =(float*)(ws+600512);
  int*   rowptr =(int*)  (ws+601024);          // 3*RPS ints
  int*   cursor =(int*)  (ws+1201088);
  int*   csr    =(int*)  (ws+1801088);         // 900000 ints
  float* wbuf   =(float*)(ws+5401088);         // 31064 f
  int*   bsums  =(int*)  (ws+5525344);         // 39 ints
  unsigned short* Abf =(unsigned short*)(ws+5526528);  // NN*64 bf16 = 6.4MB
  unsigned short* Ybf =(unsigned short*)(ws+11926528UL); // NN*256 bf16 = 25.6MB
  float* hacc   =(float*)(ws+37526528UL);      // NN*64 f
  float* xbuf   =(float*)(ws+50326528UL);      // NN*64 f
  float* EL     =(float*)(ws+63126528UL);      // NN*8 f
  float4* coef  =(float4*)(ws+64726528UL);     // 400000 float4

  hipMemsetAsync(ws, 0, 601024, stream);  // hist + both stats buffers

  k_hist<<<(E_RES+255)/256,256,0,stream>>>(dst_res,E_RES,hist);
  k_hist<<<(E_SEQ+255)/256,256,0,stream>>>(dst_seq,E_SEQ,hist+NN);
  k_hist<<<(E_KNN+255)/256,256,0,stream>>>(dst_knn,E_KNN,hist+2*NN);
  k_blocksum<<<3*SNB,256,0,stream>>>(hist,bsums);
  k_scanwrite<<<3*SNB,256,0,stream>>>(hist,bsums,rowptr,cursor);
  k_scatter<<<(E_RES+255)/256,256,0,stream>>>(src_res,dst_res,E_RES,cursor,csr);
  k_scatter<<<(E_SEQ+255)/256,256,0,stream>>>(src_seq,dst_seq,E_SEQ,cursor+NN,csr+E_RES);
  k_scatter<<<(E_KNN+255)/256,256,0,stream>>>(src_knn,dst_knn,E_KNN,cursor+2*NN,csr+E_RES+E_SEQ);

  const int MBLK=(NN+63)/64;   // 782
  const int NBLK=(NN+255)/256; // 196
  const int CBLK=(NN*64)/(256*4); // 3125 (exact)
  // ---- layer 1 ----
  k_bnstats<<<256,256,0,stream>>>(x,stats0);
  k_prep2<<<22,256,0,stream>>>(stats0,g0,be0,W0,al0,ar0,b0,rW0,wbuf);
  k_cast<<<CBLK,256,0,stream>>>(x,Abf);
  k_matmul64<<<MBLK,256,0,stream>>>(x,wbuf,wbuf+4096,hacc,0);   // residual+bias, head-meaned
  for(int r=0;r<3;r++){
    float* fr=wbuf+4160+r*WRSTRIDE;
    int csroff=(r==0)?0:(r==1)?E_RES:(E_RES+E_SEQ);
    k_mfmaC<<<MBLK,256,0,stream>>>(Abf,fr,Ybf);
    k_el<<<NBLK,256,0,stream>>>(x,fr,EL);
    k_edgecoef<<<NBLK,256,0,stream>>>(EL,rowptr+r*RPS,csr+csroff,coef);
    k_agg2<<<(NN*64)/256,256,0,stream>>>(Ybf,rowptr+r*RPS,csr+csroff,coef,hacc);
  }
  k_matmul64<<<MBLK,256,0,stream>>>(hacc,fcW0,fcb0,xbuf,1);
  // ---- layer 2 ----
  k_bnstats<<<256,256,0,stream>>>(xbuf,stats1);
  k_prep2<<<22,256,0,stream>>>(stats1,g1,be1,W1,al1,ar1,b1,rW1,wbuf);
  k_cast<<<CBLK,256,0,stream>>>(xbuf,Abf);
  k_matmul64<<<MBLK,256,0,stream>>>(xbuf,wbuf,wbuf+4096,hacc,0);
  for(int r=0;r<3;r++){
    float* fr=wbuf+4160+r*WRSTRIDE;
    int csroff=(r==0)?0:(r==1)?E_RES:(E_RES+E_SEQ);
    k_mfmaC<<<MBLK,256,0,stream>>>(Abf,fr,Ybf);
    k_el<<<NBLK,256,0,stream>>>(xbuf,fr,EL);
    k_edgecoef<<<NBLK,256,0,stream>>>(EL,rowptr+r*RPS,csr+csroff,coef);
    k_agg2<<<(NN*64)/256,256,0,stream>>>(Ybf,rowptr+r*RPS,csr+csroff,coef,hacc);
  }
  k_matmul64<<<MBLK,256,0,stream>>>(hacc,fcW1,fcb1,(float*)d_out,1);
}